// Round 1
// baseline (6334.776 us; speedup 1.0000x reference)
//
#include <hip/hip_runtime.h>
#include <hip/hip_bf16.h>

#define N_NODES 100000
#define N_EDGES 1600000

// ---------------- degree ----------------
__global__ void count_deg_kernel(const int* __restrict__ dst, int* __restrict__ deg) {
    int i = blockIdx.x * blockDim.x + threadIdx.x;
    if (i < N_EDGES) atomicAdd(&deg[dst[i]], 1);
}

// deg (int, in-degree) -> dinv (float) in place: dinv = 1/sqrt(deg+1)
__global__ void dinv_kernel(float* __restrict__ buf) {
    int i = blockIdx.x * blockDim.x + threadIdx.x;
    if (i < N_NODES) {
        int c = ((const int*)buf)[i];
        buf[i] = 1.0f / sqrtf((float)c + 1.0f);
    }
}

// ---------------- fp32 tiled GEMM: C[N,M] = A[N,K] @ W[K,M] ----------------
template<int K, int M, int BN, int TN>
__global__ __launch_bounds__(256) void gemm_kernel(const float* __restrict__ A,
                                                   const float* __restrict__ W,
                                                   float* __restrict__ C) {
    constexpr int BM = 64;   // rows per block
    constexpr int BK = 16;
    constexpr int TM = 4;    // rows per thread
    __shared__ float As[BK][BM];
    __shared__ float Bs[BK][BN];
    const int tid = threadIdx.x;
    const int tx = tid % (BN / TN);   // 16 col-threads
    const int ty = tid / (BN / TN);   // 16 row-threads
    const int row0 = blockIdx.y * BM;
    const int col0 = blockIdx.x * BN;

    float acc[TM][TN] = {};
    for (int k0 = 0; k0 < K; k0 += BK) {
        // stage A tile (BM x BK), transposed into As[k][m]
        #pragma unroll
        for (int i = tid; i < BM * BK; i += 256) {
            int ar = i / BK, ak = i % BK;
            int gr = row0 + ar; if (gr >= N_NODES) gr = N_NODES - 1;
            As[ak][ar] = A[(size_t)gr * K + k0 + ak];
        }
        // stage W tile (BK x BN)
        #pragma unroll
        for (int i = tid; i < BK * BN; i += 256) {
            int bk = i / BN, bc = i % BN;
            Bs[bk][bc] = W[(size_t)(k0 + bk) * M + col0 + bc];
        }
        __syncthreads();
        #pragma unroll
        for (int kk = 0; kk < BK; ++kk) {
            float a[TM], b[TN];
            #pragma unroll
            for (int i = 0; i < TM; ++i) a[i] = As[kk][ty * TM + i];
            #pragma unroll
            for (int j = 0; j < TN; ++j) b[j] = Bs[kk][tx * TN + j];
            #pragma unroll
            for (int i = 0; i < TM; ++i)
                #pragma unroll
                for (int j = 0; j < TN; ++j)
                    acc[i][j] = fmaf(a[i], b[j], acc[i][j]);
        }
        __syncthreads();
    }
    #pragma unroll
    for (int i = 0; i < TM; ++i) {
        int gr = row0 + ty * TM + i;
        if (gr < N_NODES) {
            #pragma unroll
            for (int j = 0; j < TN; ++j)
                C[(size_t)gr * M + col0 + tx * TN + j] = acc[i][j];
        }
    }
}

// ---------------- out = h*selfnorm + bias (initializes agg buffer) ----------------
template<int M>
__global__ void self_init_kernel(const float* __restrict__ h, const float* __restrict__ dinv,
                                 const float* __restrict__ bias, float* __restrict__ out) {
    int i = blockIdx.x * blockDim.x + threadIdx.x;   // float4 index
    constexpr int C4 = M / 4;
    if (i >= N_NODES * C4) return;
    int n = i / C4;
    int c4 = i % C4;
    float s = dinv[n]; s = s * s;
    float4 v = ((const float4*)h)[i];
    float4 b = ((const float4*)bias)[c4];
    float4 o;
    o.x = v.x * s + b.x; o.y = v.y * s + b.y;
    o.z = v.z * s + b.z; o.w = v.w * s + b.w;
    ((float4*)out)[i] = o;
}

// ---------------- edge scatter-add: out[dst] += h[src] * dinv[src]*dinv[dst] ----------------
template<int M>
__global__ void scatter_add_kernel(const int* __restrict__ esrc, const int* __restrict__ edst,
                                   const float* __restrict__ dinv, const float* __restrict__ h,
                                   float* __restrict__ out) {
    constexpr int CH = M / 4;   // float4 chunks per edge
    int t = blockIdx.x * blockDim.x + threadIdx.x;
    if (t >= N_EDGES * CH) return;
    int e = t / CH, c = t % CH;
    int s = esrc[e], d = edst[e];
    float nm = dinv[s] * dinv[d];
    float4 v = ((const float4*)(h + (size_t)s * M))[c];
    float* o = out + (size_t)d * M + c * 4;
    unsafeAtomicAdd(o + 0, v.x * nm);
    unsafeAtomicAdd(o + 1, v.y * nm);
    unsafeAtomicAdd(o + 2, v.z * nm);
    unsafeAtomicAdd(o + 3, v.w * nm);
}

// ---------------- log_softmax over 32 classes ----------------
__global__ void log_softmax32_kernel(const float* __restrict__ in, float* __restrict__ out) {
    int t = blockIdx.x * blockDim.x + threadIdx.x;
    int row = t >> 5;
    if (row >= N_NODES) return;
    float v = in[t];
    float m = v;
    #pragma unroll
    for (int o = 16; o; o >>= 1) m = fmaxf(m, __shfl_xor(m, o, 32));
    float e = expf(v - m);
    float s = e;
    #pragma unroll
    for (int o = 16; o; o >>= 1) s += __shfl_xor(s, o, 32);
    out[t] = v - m - logf(s);
}

extern "C" void kernel_launch(void* const* d_in, const int* in_sizes, int n_in,
                              void* d_out, int out_size, void* d_ws, size_t ws_size,
                              hipStream_t stream) {
    const float* x  = (const float*)d_in[0];
    const int*   ei = (const int*)d_in[1];     // [2, E] int32
    const float* W0 = (const float*)d_in[2];
    const float* b0 = (const float*)d_in[3];
    const float* W1 = (const float*)d_in[4];
    const float* b1 = (const float*)d_in[5];
    const float* W2 = (const float*)d_in[6];
    const float* b2 = (const float*)d_in[7];
    float* out = (float*)d_out;

    char* ws = (char*)d_ws;
    float* dinv = (float*)ws;                               // 400 KB
    float* bufA = (float*)(ws + (1 << 20));                 // 51.2 MB (GEMM out h)
    float* bufB = (float*)(ws + (1 << 20) + 51200000);      // 51.2 MB (agg / layer out)
    const int* esrc = ei;
    const int* edst = ei + N_EDGES;

    // degree -> dinv
    hipMemsetAsync(dinv, 0, N_NODES * sizeof(int), stream);
    count_deg_kernel<<<N_EDGES / 256, 256, 0, stream>>>(edst, (int*)dinv);
    dinv_kernel<<<(N_NODES + 255) / 256, 256, 0, stream>>>(dinv);

    const int ROWB = (N_NODES + 63) / 64;   // 1563

    // ---- layer 0: x[100k,256] @ W0[256,128] ----
    gemm_kernel<256, 128, 64, 4><<<dim3(2, ROWB), 256, 0, stream>>>(x, W0, bufA);
    self_init_kernel<128><<<(N_NODES * 32 + 255) / 256, 256, 0, stream>>>(bufA, dinv, b0, bufB);
    scatter_add_kernel<128><<<N_EDGES * 32 / 256, 256, 0, stream>>>(esrc, edst, dinv, bufA, bufB);

    // ---- layer 1: H1[100k,128] @ W1[128,128] ----
    gemm_kernel<128, 128, 64, 4><<<dim3(2, ROWB), 256, 0, stream>>>(bufB, W1, bufA);
    self_init_kernel<128><<<(N_NODES * 32 + 255) / 256, 256, 0, stream>>>(bufA, dinv, b1, bufB);
    scatter_add_kernel<128><<<N_EDGES * 32 / 256, 256, 0, stream>>>(esrc, edst, dinv, bufA, bufB);

    // ---- layer 2: H2[100k,128] @ W2[128,32] ----
    gemm_kernel<128, 32, 32, 2><<<dim3(1, ROWB), 256, 0, stream>>>(bufB, W2, bufA);
    self_init_kernel<32><<<(N_NODES * 8 + 255) / 256, 256, 0, stream>>>(bufA, dinv, b2, bufB);
    scatter_add_kernel<32><<<N_EDGES * 8 / 256, 256, 0, stream>>>(esrc, edst, dinv, bufA, bufB);

    // ---- log_softmax ----
    log_softmax32_kernel<<<N_NODES * 32 / 256 + 1, 256, 0, stream>>>(bufB, out);
}

// Round 2
// 821.992 us; speedup vs baseline: 7.7066x; 7.7066x over previous
//
#include <hip/hip_runtime.h>
#include <hip/hip_bf16.h>

#define N_NODES 100000
#define N_EDGES 1600000

// ---------------- degree count (in-degree at dst) ----------------
__global__ void count_deg_kernel(const int* __restrict__ dst, int* __restrict__ deg) {
    int i = blockIdx.x * blockDim.x + threadIdx.x;
    if (i < N_EDGES) atomicAdd(&deg[dst[i]], 1);
}

__global__ void dinv_kernel(const int* __restrict__ deg, float* __restrict__ dinv) {
    int i = blockIdx.x * blockDim.x + threadIdx.x;
    if (i < N_NODES) dinv[i] = 1.0f / sqrtf((float)deg[i] + 1.0f);
}

// ---------------- CSR build: block scan -> partial scan -> add ----------------
__global__ void block_scan_kernel(const int* __restrict__ deg, int* __restrict__ rowptr,
                                  int* __restrict__ bsums) {
    __shared__ int s[256];
    int i = blockIdx.x * 256 + threadIdx.x;
    int v = (i < N_NODES) ? deg[i] : 0;
    s[threadIdx.x] = v;
    __syncthreads();
    #pragma unroll
    for (int off = 1; off < 256; off <<= 1) {
        int t = (threadIdx.x >= off) ? s[threadIdx.x - off] : 0;
        __syncthreads();
        s[threadIdx.x] += t;
        __syncthreads();
    }
    if (i < N_NODES) rowptr[i] = s[threadIdx.x] - v;   // exclusive within block
    if (threadIdx.x == 255) bsums[blockIdx.x] = s[255];
}

__global__ void scan_bsums_kernel(int* __restrict__ bsums, int nB) {
    __shared__ int s[512];
    int tid = threadIdx.x;
    int v = (tid < nB) ? bsums[tid] : 0;
    s[tid] = v;
    __syncthreads();
    #pragma unroll
    for (int off = 1; off < 512; off <<= 1) {
        int t = (tid >= off) ? s[tid - off] : 0;
        __syncthreads();
        s[tid] += t;
        __syncthreads();
    }
    if (tid < nB) bsums[tid] = s[tid] - v;             // exclusive
}

__global__ void add_offsets_kernel(int* __restrict__ rowptr, const int* __restrict__ bsums,
                                   int* __restrict__ cursor) {
    int i = blockIdx.x * 256 + threadIdx.x;
    if (i < N_NODES) {
        int r = rowptr[i] + bsums[blockIdx.x];
        rowptr[i] = r;
        cursor[i] = r;
    }
    if (i == 0) rowptr[N_NODES] = N_EDGES;
}

__global__ void fill_kernel(const int* __restrict__ esrc, const int* __restrict__ edst,
                            int* __restrict__ cursor, int* __restrict__ esorted) {
    int e = blockIdx.x * 256 + threadIdx.x;
    if (e < N_EDGES) {
        int pos = atomicAdd(&cursor[edst[e]], 1);
        esorted[pos] = esrc[e];
    }
}

// ---------------- fp32 tiled GEMM: C[N,M] = A[N,K] @ W[K,M] ----------------
template<int K, int M, int BN, int TN>
__global__ __launch_bounds__(256) void gemm_kernel(const float* __restrict__ A,
                                                   const float* __restrict__ W,
                                                   float* __restrict__ C) {
    constexpr int BM = 64;
    constexpr int BK = 16;
    constexpr int TM = 4;
    __shared__ float As[BK][BM];
    __shared__ float Bs[BK][BN];
    const int tid = threadIdx.x;
    const int tx = tid % (BN / TN);
    const int ty = tid / (BN / TN);
    const int row0 = blockIdx.y * BM;
    const int col0 = blockIdx.x * BN;

    float acc[TM][TN] = {};
    for (int k0 = 0; k0 < K; k0 += BK) {
        #pragma unroll
        for (int i = tid; i < BM * BK; i += 256) {
            int ar = i / BK, ak = i % BK;
            int gr = row0 + ar; if (gr >= N_NODES) gr = N_NODES - 1;
            As[ak][ar] = A[(size_t)gr * K + k0 + ak];
        }
        #pragma unroll
        for (int i = tid; i < BK * BN; i += 256) {
            int bk = i / BN, bc = i % BN;
            Bs[bk][bc] = W[(size_t)(k0 + bk) * M + col0 + bc];
        }
        __syncthreads();
        #pragma unroll
        for (int kk = 0; kk < BK; ++kk) {
            float a[TM], b[TN];
            #pragma unroll
            for (int i = 0; i < TM; ++i) a[i] = As[kk][ty * TM + i];
            #pragma unroll
            for (int j = 0; j < TN; ++j) b[j] = Bs[kk][tx * TN + j];
            #pragma unroll
            for (int i = 0; i < TM; ++i)
                #pragma unroll
                for (int j = 0; j < TN; ++j)
                    acc[i][j] = fmaf(a[i], b[j], acc[i][j]);
        }
        __syncthreads();
    }
    #pragma unroll
    for (int i = 0; i < TM; ++i) {
        int gr = row0 + ty * TM + i;
        if (gr < N_NODES) {
            #pragma unroll
            for (int j = 0; j < TN; ++j)
                C[(size_t)gr * M + col0 + tx * TN + j] = acc[i][j];
        }
    }
}

// ---------------- CSR gather aggregation + self-loop + bias ----------------
// G lanes per node, each lane owns one float2 chunk (M == 2*G)
template<int M, int G>
__global__ __launch_bounds__(256) void gather_kernel(const int* __restrict__ rowptr,
                                                     const int* __restrict__ esorted,
                                                     const float* __restrict__ dinv,
                                                     const float* __restrict__ h,
                                                     const float* __restrict__ bias,
                                                     float* __restrict__ out) {
    static_assert(M == 2 * G, "layout");
    int gid = blockIdx.x * blockDim.x + threadIdx.x;
    int node = gid / G;
    int lane = gid % G;
    if (node >= N_NODES) return;
    int beg = rowptr[node], end = rowptr[node + 1];
    float dn = dinv[node];
    const float2* hp = (const float2*)h;
    float2 acc = make_float2(0.f, 0.f);
    for (int j = beg; j < end; ++j) {
        int s = esorted[j];
        float nm = dinv[s] * dn;
        float2 v = hp[(size_t)s * G + lane];
        acc.x += v.x * nm;
        acc.y += v.y * nm;
    }
    float2 hv = hp[(size_t)node * G + lane];
    float sn = dn * dn;
    float2 b = ((const float2*)bias)[lane];
    acc.x += hv.x * sn + b.x;
    acc.y += hv.y * sn + b.y;
    ((float2*)out)[(size_t)node * G + lane] = acc;
}

// ---------------- log_softmax over 32 classes ----------------
__global__ void log_softmax32_kernel(const float* __restrict__ in, float* __restrict__ out) {
    int t = blockIdx.x * blockDim.x + threadIdx.x;
    int row = t >> 5;
    if (row >= N_NODES) return;
    float v = in[t];
    float m = v;
    #pragma unroll
    for (int o = 16; o; o >>= 1) m = fmaxf(m, __shfl_xor(m, o, 32));
    float e = expf(v - m);
    float s = e;
    #pragma unroll
    for (int o = 16; o; o >>= 1) s += __shfl_xor(s, o, 32);
    out[t] = v - m - logf(s);
}

extern "C" void kernel_launch(void* const* d_in, const int* in_sizes, int n_in,
                              void* d_out, int out_size, void* d_ws, size_t ws_size,
                              hipStream_t stream) {
    const float* x  = (const float*)d_in[0];
    const int*   ei = (const int*)d_in[1];     // [2, E] int32
    const float* W0 = (const float*)d_in[2];
    const float* b0 = (const float*)d_in[3];
    const float* W1 = (const float*)d_in[4];
    const float* b1 = (const float*)d_in[5];
    const float* W2 = (const float*)d_in[6];
    const float* b2 = (const float*)d_in[7];
    float* out = (float*)d_out;

    char* ws = (char*)d_ws;
    float* dinv    = (float*)(ws + 0);                  // 400 KB
    int*   deg     = (int*)  (ws + (512 << 10));        // 400 KB (reused as cursor)
    int*   rowptr  = (int*)  (ws + (1 << 20));          // 400 KB + 4
    int*   bsums   = (int*)  (ws + (1536 << 10));       // ~1.6 KB
    int*   esorted = (int*)  (ws + (2 << 20));          // 6.4 MB
    float* bufA    = (float*)(ws + 9437184);            // 51.2 MB
    float* bufB    = (float*)(ws + 9437184 + 51200000); // 51.2 MB (ends ~106.7 MiB)
    const int* esrc = ei;
    const int* edst = ei + N_EDGES;

    const int NB = (N_NODES + 255) / 256;   // 391

    // ---- degree / dinv / CSR ----
    hipMemsetAsync(deg, 0, N_NODES * sizeof(int), stream);
    count_deg_kernel<<<N_EDGES / 256, 256, 0, stream>>>(edst, deg);
    dinv_kernel<<<NB, 256, 0, stream>>>(deg, dinv);
    block_scan_kernel<<<NB, 256, 0, stream>>>(deg, rowptr, bsums);
    scan_bsums_kernel<<<1, 512, 0, stream>>>(bsums, NB);
    add_offsets_kernel<<<NB, 256, 0, stream>>>(rowptr, bsums, deg /*cursor*/);
    fill_kernel<<<N_EDGES / 256, 256, 0, stream>>>(esrc, edst, deg /*cursor*/, esorted);

    const int ROWB = (N_NODES + 63) / 64;   // 1563

    // ---- layer 0: x[100k,256] @ W0 -> h ; aggregate ----
    gemm_kernel<256, 128, 64, 4><<<dim3(2, ROWB), 256, 0, stream>>>(x, W0, bufA);
    gather_kernel<128, 64><<<(N_NODES * 64 + 255) / 256, 256, 0, stream>>>(
        rowptr, esorted, dinv, bufA, b0, bufB);

    // ---- layer 1 ----
    gemm_kernel<128, 128, 64, 4><<<dim3(2, ROWB), 256, 0, stream>>>(bufB, W1, bufA);
    gather_kernel<128, 64><<<(N_NODES * 64 + 255) / 256, 256, 0, stream>>>(
        rowptr, esorted, dinv, bufA, b1, bufB);

    // ---- layer 2 ----
    gemm_kernel<128, 32, 32, 2><<<dim3(1, ROWB), 256, 0, stream>>>(bufB, W2, bufA);
    gather_kernel<32, 16><<<(N_NODES * 16 + 255) / 256, 256, 0, stream>>>(
        rowptr, esorted, dinv, bufA, b2, bufB);

    // ---- log_softmax ----
    log_softmax32_kernel<<<N_NODES * 32 / 256 + 1, 256, 0, stream>>>(bufB, out);
}

// Round 3
// 676.074 us; speedup vs baseline: 9.3699x; 1.2158x over previous
//
#include <hip/hip_runtime.h>
#include <hip/hip_bf16.h>

#define N_NODES 100000
#define N_EDGES 1600000

// ---------------- degree count (in-degree at dst) ----------------
__global__ void count_deg_kernel(const int* __restrict__ dst, int* __restrict__ deg) {
    int i = blockIdx.x * blockDim.x + threadIdx.x;
    if (i < N_EDGES) atomicAdd(&deg[dst[i]], 1);
}

__global__ void dinv_kernel(const int* __restrict__ deg, float* __restrict__ dinv) {
    int i = blockIdx.x * blockDim.x + threadIdx.x;
    if (i < N_NODES) dinv[i] = 1.0f / sqrtf((float)deg[i] + 1.0f);
}

// ---------------- CSR build: block scan -> partial scan -> add ----------------
__global__ void block_scan_kernel(const int* __restrict__ deg, int* __restrict__ rowptr,
                                  int* __restrict__ bsums) {
    __shared__ int s[256];
    int i = blockIdx.x * 256 + threadIdx.x;
    int v = (i < N_NODES) ? deg[i] : 0;
    s[threadIdx.x] = v;
    __syncthreads();
    #pragma unroll
    for (int off = 1; off < 256; off <<= 1) {
        int t = (threadIdx.x >= off) ? s[threadIdx.x - off] : 0;
        __syncthreads();
        s[threadIdx.x] += t;
        __syncthreads();
    }
    if (i < N_NODES) rowptr[i] = s[threadIdx.x] - v;   // exclusive within block
    if (threadIdx.x == 255) bsums[blockIdx.x] = s[255];
}

__global__ void scan_bsums_kernel(int* __restrict__ bsums, int nB) {
    __shared__ int s[512];
    int tid = threadIdx.x;
    int v = (tid < nB) ? bsums[tid] : 0;
    s[tid] = v;
    __syncthreads();
    #pragma unroll
    for (int off = 1; off < 512; off <<= 1) {
        int t = (tid >= off) ? s[tid - off] : 0;
        __syncthreads();
        s[tid] += t;
        __syncthreads();
    }
    if (tid < nB) bsums[tid] = s[tid] - v;             // exclusive
}

__global__ void add_offsets_kernel(int* __restrict__ rowptr, const int* __restrict__ bsums,
                                   int* __restrict__ cursor) {
    int i = blockIdx.x * 256 + threadIdx.x;
    if (i < N_NODES) {
        int r = rowptr[i] + bsums[blockIdx.x];
        rowptr[i] = r;
        cursor[i] = r;
    }
    if (i == 0) rowptr[N_NODES] = N_EDGES;
}

__global__ void fill_kernel(const int* __restrict__ esrc, const int* __restrict__ edst,
                            int* __restrict__ cursor, int* __restrict__ esorted) {
    int e = blockIdx.x * 256 + threadIdx.x;
    if (e < N_EDGES) {
        int pos = atomicAdd(&cursor[edst[e]], 1);
        esorted[pos] = esrc[e];
    }
}

// ---------------- fp32 tiled GEMM, epilogue scales rows by dinv ----------------
// C[r, :] = (A @ W)[r, :] * dinv[r]
template<int K, int M, int BM, int BN, int BK, int TM, int TN>
__global__ __launch_bounds__(256) void gemm_scaled_kernel(const float* __restrict__ A,
                                                          const float* __restrict__ W,
                                                          const float* __restrict__ dinv,
                                                          float* __restrict__ C) {
    static_assert((BM / TM) * (BN / TN) == 256, "thread grid");
    static_assert(BK % 4 == 0 && BN % 4 == 0, "vec4");
    __shared__ float As[BK][BM + 4];   // +4 pad keeps rows 16B-aligned, breaks conflicts
    __shared__ float Bs[BK][BN];
    const int tid = threadIdx.x;
    const int tx = tid % (BN / TN);
    const int ty = tid / (BN / TN);
    const int row0 = blockIdx.y * BM;
    const int col0 = blockIdx.x * BN;

    float acc[TM][TN] = {};
    for (int k0 = 0; k0 < K; k0 += BK) {
        // stage A tile: BM rows x BK k, float4 along K, transpose into As[k][m]
        constexpr int A4 = BM * BK / 4;
        #pragma unroll
        for (int i = tid; i < A4; i += 256) {
            int ar = i / (BK / 4);
            int a4 = i % (BK / 4);
            int gr = row0 + ar; if (gr >= N_NODES) gr = N_NODES - 1;
            float4 v = *(const float4*)&A[(size_t)gr * K + k0 + a4 * 4];
            As[a4 * 4 + 0][ar] = v.x;
            As[a4 * 4 + 1][ar] = v.y;
            As[a4 * 4 + 2][ar] = v.z;
            As[a4 * 4 + 3][ar] = v.w;
        }
        // stage W tile: BK x BN, float4 along N
        constexpr int B4 = BK * BN / 4;
        #pragma unroll
        for (int i = tid; i < B4; i += 256) {
            int bk = i / (BN / 4);
            int b4 = i % (BN / 4);
            *(float4*)&Bs[bk][b4 * 4] = *(const float4*)&W[(size_t)(k0 + bk) * M + col0 + b4 * 4];
        }
        __syncthreads();
        #pragma unroll
        for (int kk = 0; kk < BK; ++kk) {
            float a[TM], b[TN];
            #pragma unroll
            for (int i = 0; i < TM; ++i) a[i] = As[kk][ty * TM + i];
            #pragma unroll
            for (int j = 0; j < TN; ++j) b[j] = Bs[kk][tx * TN + j];
            #pragma unroll
            for (int i = 0; i < TM; ++i)
                #pragma unroll
                for (int j = 0; j < TN; ++j)
                    acc[i][j] = fmaf(a[i], b[j], acc[i][j]);
        }
        __syncthreads();
    }
    #pragma unroll
    for (int i = 0; i < TM; ++i) {
        int gr = row0 + ty * TM + i;
        if (gr >= N_NODES) continue;
        float s = dinv[gr];
        float* cp = &C[(size_t)gr * M + col0 + tx * TN];
        if constexpr (TN % 4 == 0) {
            #pragma unroll
            for (int j4 = 0; j4 < TN / 4; ++j4) {
                float4 o;
                o.x = acc[i][j4 * 4 + 0] * s;
                o.y = acc[i][j4 * 4 + 1] * s;
                o.z = acc[i][j4 * 4 + 2] * s;
                o.w = acc[i][j4 * 4 + 3] * s;
                ((float4*)cp)[j4] = o;
            }
        } else {
            float2 o;
            o.x = acc[i][0] * s;
            o.y = acc[i][1] * s;
            *(float2*)cp = o;
        }
    }
}

// ---------------- CSR gather: out[n] = dinv[n]*(sum hs[src] + hs[n]) + b ----------------
// G lanes per node, each lane owns one float2 chunk (M == 2*G)
template<int M, int G>
__global__ __launch_bounds__(256) void gather_kernel(const int* __restrict__ rowptr,
                                                     const int* __restrict__ esorted,
                                                     const float* __restrict__ dinv,
                                                     const float* __restrict__ hs,
                                                     const float* __restrict__ bias,
                                                     float* __restrict__ out) {
    static_assert(M == 2 * G, "layout");
    int gid = blockIdx.x * blockDim.x + threadIdx.x;
    int node = gid / G;
    int lane = gid % G;
    if (node >= N_NODES) return;
    int beg = rowptr[node], end = rowptr[node + 1];
    float dn = dinv[node];
    const float2* hp = (const float2*)hs;
    float2 acc = hp[(size_t)node * G + lane];   // self term (hs[n])
    int j = beg;
    for (; j + 4 <= end; j += 4) {
        int s0 = esorted[j + 0];
        int s1 = esorted[j + 1];
        int s2 = esorted[j + 2];
        int s3 = esorted[j + 3];
        float2 v0 = hp[(size_t)s0 * G + lane];
        float2 v1 = hp[(size_t)s1 * G + lane];
        float2 v2 = hp[(size_t)s2 * G + lane];
        float2 v3 = hp[(size_t)s3 * G + lane];
        acc.x += (v0.x + v1.x) + (v2.x + v3.x);
        acc.y += (v0.y + v1.y) + (v2.y + v3.y);
    }
    for (; j < end; ++j) {
        int s = esorted[j];
        float2 v = hp[(size_t)s * G + lane];
        acc.x += v.x;
        acc.y += v.y;
    }
    float2 b = ((const float2*)bias)[lane];
    float2 o;
    o.x = acc.x * dn + b.x;
    o.y = acc.y * dn + b.y;
    ((float2*)out)[(size_t)node * G + lane] = o;
}

// ---------------- log_softmax over 32 classes ----------------
__global__ void log_softmax32_kernel(const float* __restrict__ in, float* __restrict__ out) {
    int t = blockIdx.x * blockDim.x + threadIdx.x;
    int row = t >> 5;
    if (row >= N_NODES) return;
    float v = in[t];
    float m = v;
    #pragma unroll
    for (int o = 16; o; o >>= 1) m = fmaxf(m, __shfl_xor(m, o, 32));
    float e = expf(v - m);
    float s = e;
    #pragma unroll
    for (int o = 16; o; o >>= 1) s += __shfl_xor(s, o, 32);
    out[t] = v - m - logf(s);
}

extern "C" void kernel_launch(void* const* d_in, const int* in_sizes, int n_in,
                              void* d_out, int out_size, void* d_ws, size_t ws_size,
                              hipStream_t stream) {
    const float* x  = (const float*)d_in[0];
    const int*   ei = (const int*)d_in[1];     // [2, E] int32
    const float* W0 = (const float*)d_in[2];
    const float* b0 = (const float*)d_in[3];
    const float* W1 = (const float*)d_in[4];
    const float* b1 = (const float*)d_in[5];
    const float* W2 = (const float*)d_in[6];
    const float* b2 = (const float*)d_in[7];
    float* out = (float*)d_out;

    char* ws = (char*)d_ws;
    float* dinv    = (float*)(ws + 0);                  // 400 KB
    int*   deg     = (int*)  (ws + (512 << 10));        // 400 KB (reused as cursor)
    int*   rowptr  = (int*)  (ws + (1 << 20));          // 400 KB + 4
    int*   bsums   = (int*)  (ws + (1536 << 10));       // ~1.6 KB
    int*   esorted = (int*)  (ws + (2 << 20));          // 6.4 MB
    float* bufA    = (float*)(ws + 9437184);            // 51.2 MB
    float* bufB    = (float*)(ws + 9437184 + 51200000); // 51.2 MB
    const int* esrc = ei;
    const int* edst = ei + N_EDGES;

    const int NB = (N_NODES + 255) / 256;   // 391

    // ---- degree / dinv / CSR ----
    hipMemsetAsync(deg, 0, N_NODES * sizeof(int), stream);
    count_deg_kernel<<<N_EDGES / 256, 256, 0, stream>>>(edst, deg);
    dinv_kernel<<<NB, 256, 0, stream>>>(deg, dinv);
    block_scan_kernel<<<NB, 256, 0, stream>>>(deg, rowptr, bsums);
    scan_bsums_kernel<<<1, 512, 0, stream>>>(bsums, NB);
    add_offsets_kernel<<<NB, 256, 0, stream>>>(rowptr, bsums, deg /*cursor*/);
    fill_kernel<<<N_EDGES / 256, 256, 0, stream>>>(esrc, edst, deg /*cursor*/, esorted);

    const int RB128 = (N_NODES + 127) / 128;   // 782

    // ---- layer 0: hs = (x @ W0) * dinv ; aggregate ----
    gemm_scaled_kernel<256, 128, 128, 128, 16, 8, 8>
        <<<dim3(1, RB128), 256, 0, stream>>>(x, W0, dinv, bufA);
    gather_kernel<128, 64><<<(N_NODES * 64 + 255) / 256, 256, 0, stream>>>(
        rowptr, esorted, dinv, bufA, b0, bufB);

    // ---- layer 1 ----
    gemm_scaled_kernel<128, 128, 128, 128, 16, 8, 8>
        <<<dim3(1, RB128), 256, 0, stream>>>(bufB, W1, dinv, bufA);
    gather_kernel<128, 64><<<(N_NODES * 64 + 255) / 256, 256, 0, stream>>>(
        rowptr, esorted, dinv, bufA, b1, bufB);

    // ---- layer 2 ----
    gemm_scaled_kernel<128, 32, 128, 32, 16, 8, 2>
        <<<dim3(1, RB128), 256, 0, stream>>>(bufB, W2, dinv, bufA);
    gather_kernel<32, 16><<<(N_NODES * 16 + 255) / 256, 256, 0, stream>>>(
        rowptr, esorted, dinv, bufA, b2, bufB);

    // ---- log_softmax ----
    log_softmax32_kernel<<<N_NODES * 32 / 256 + 1, 256, 0, stream>>>(bufB, out);
}

// Round 5
// 637.586 us; speedup vs baseline: 9.9356x; 1.0604x over previous
//
#include <hip/hip_runtime.h>
#include <hip/hip_bf16.h>

#define N_NODES 100000
#define N_EDGES 1600000

typedef __bf16 bf16x8 __attribute__((ext_vector_type(8)));
typedef float f32x4 __attribute__((ext_vector_type(4)));
typedef unsigned short u16x8 __attribute__((ext_vector_type(8)));
typedef unsigned short u16x4 __attribute__((ext_vector_type(4)));

// ---------------- degree count (in-degree at dst) ----------------
__global__ void count_deg_kernel(const int* __restrict__ dst, int* __restrict__ deg) {
    int i = blockIdx.x * blockDim.x + threadIdx.x;
    if (i < N_EDGES) atomicAdd(&deg[dst[i]], 1);
}

__global__ void dinv_kernel(const int* __restrict__ deg, float* __restrict__ dinv) {
    int i = blockIdx.x * blockDim.x + threadIdx.x;
    if (i < N_NODES) dinv[i] = 1.0f / sqrtf((float)deg[i] + 1.0f);
}

// ---------------- CSR build: block scan -> partial scan -> add ----------------
__global__ void block_scan_kernel(const int* __restrict__ deg, int* __restrict__ rowptr,
                                  int* __restrict__ bsums) {
    __shared__ int s[256];
    int i = blockIdx.x * 256 + threadIdx.x;
    int v = (i < N_NODES) ? deg[i] : 0;
    s[threadIdx.x] = v;
    __syncthreads();
    #pragma unroll
    for (int off = 1; off < 256; off <<= 1) {
        int t = (threadIdx.x >= off) ? s[threadIdx.x - off] : 0;
        __syncthreads();
        s[threadIdx.x] += t;
        __syncthreads();
    }
    if (i < N_NODES) rowptr[i] = s[threadIdx.x] - v;   // exclusive within block
    if (threadIdx.x == 255) bsums[blockIdx.x] = s[255];
}

__global__ void scan_bsums_kernel(int* __restrict__ bsums, int nB) {
    __shared__ int s[512];
    int tid = threadIdx.x;
    int v = (tid < nB) ? bsums[tid] : 0;
    s[tid] = v;
    __syncthreads();
    #pragma unroll
    for (int off = 1; off < 512; off <<= 1) {
        int t = (tid >= off) ? s[tid - off] : 0;
        __syncthreads();
        s[tid] += t;
        __syncthreads();
    }
    if (tid < nB) bsums[tid] = s[tid] - v;             // exclusive
}

__global__ void add_offsets_kernel(int* __restrict__ rowptr, const int* __restrict__ bsums,
                                   int* __restrict__ cursor) {
    int i = blockIdx.x * 256 + threadIdx.x;
    if (i < N_NODES) {
        int r = rowptr[i] + bsums[blockIdx.x];
        rowptr[i] = r;
        cursor[i] = r;
    }
    if (i == 0) rowptr[N_NODES] = N_EDGES;
}

__global__ void fill_kernel(const int* __restrict__ esrc, const int* __restrict__ edst,
                            int* __restrict__ cursor, int* __restrict__ esorted) {
    int e = blockIdx.x * 256 + threadIdx.x;
    if (e < N_EDGES) {
        int pos = atomicAdd(&cursor[edst[e]], 1);
        esorted[pos] = esrc[e];
    }
}

// ---------------- MFMA GEMM (bf16x2 split emulating fp32) ----------------
// C[r,:] = (A @ W)[r,:] * dinv[r], via Ahi@Whi + Ahi@Wlo + Alo@Whi
// returns hi in bits[15:0], lo in bits[31:16]
__device__ inline unsigned int split_bf16(float v) {
    __bf16 h = (__bf16)v;
    float r = v - (float)h;
    __bf16 l = (__bf16)r;
    unsigned int hu = __builtin_bit_cast(unsigned short, h);
    unsigned int lu = __builtin_bit_cast(unsigned short, l);
    return hu | (lu << 16);
}

template<int K, int M, int WR, int WC>
__global__ __launch_bounds__(256) void mfma_gemm_kernel(const float* __restrict__ A,
                                                        const float* __restrict__ W,
                                                        const float* __restrict__ dinv,
                                                        float* __restrict__ C) {
    constexpr int BM = 128;
    constexpr int FR = BM / (WR * 16);     // row frags per wave
    constexpr int FC = M / (WC * 16);      // col frags per wave
    constexpr int LD = 40;                 // padded k-stride (ushorts): 80B rows, 16B-aligned
    __shared__ unsigned short Ahi[BM][LD], Alo[BM][LD];
    __shared__ unsigned short Bhi[M][LD],  Blo[M][LD];   // W transposed: [col][k]

    const int tid = threadIdx.x;
    const int row0 = blockIdx.y * BM;
    const int wave = tid >> 6, lane = tid & 63;
    const int wr = wave / WC, wc = wave % WC;
    const int r0 = wr * FR * 16, c0 = wc * FC * 16;
    const int l15 = lane & 15, kof = (lane >> 4) * 8;

    f32x4 acc[FR][FC] = {};

    for (int k0 = 0; k0 < K; k0 += 32) {
        // ---- stage A tile: BM x 32 fp32 -> hi/lo bf16 ----
        #pragma unroll
        for (int i = tid; i < BM * 8; i += 256) {
            int row = i >> 3, q = i & 7;            // q*4 = k offset
            int gr = row0 + row; if (gr >= N_NODES) gr = N_NODES - 1;
            float4 v = *(const float4*)&A[(size_t)gr * K + k0 + q * 4];
            unsigned int p0 = split_bf16(v.x);
            unsigned int p1 = split_bf16(v.y);
            unsigned int p2 = split_bf16(v.z);
            unsigned int p3 = split_bf16(v.w);
            u16x4 h4, l4;
            h4[0] = (unsigned short)p0; l4[0] = (unsigned short)(p0 >> 16);
            h4[1] = (unsigned short)p1; l4[1] = (unsigned short)(p1 >> 16);
            h4[2] = (unsigned short)p2; l4[2] = (unsigned short)(p2 >> 16);
            h4[3] = (unsigned short)p3; l4[3] = (unsigned short)(p3 >> 16);
            *(u16x4*)&Ahi[row][q * 4] = h4;
            *(u16x4*)&Alo[row][q * 4] = l4;
        }
        // ---- stage W tile: 32 x M fp32 -> transposed hi/lo bf16 ----
        constexpr int BQ = M / 4;
        #pragma unroll
        for (int i = tid; i < 32 * BQ; i += 256) {
            int k = i / BQ, q = i % BQ;
            float4 v = *(const float4*)&W[(size_t)(k0 + k) * M + q * 4];
            unsigned int p;
            p = split_bf16(v.x); Bhi[q * 4 + 0][k] = (unsigned short)p; Blo[q * 4 + 0][k] = (unsigned short)(p >> 16);
            p = split_bf16(v.y); Bhi[q * 4 + 1][k] = (unsigned short)p; Blo[q * 4 + 1][k] = (unsigned short)(p >> 16);
            p = split_bf16(v.z); Bhi[q * 4 + 2][k] = (unsigned short)p; Blo[q * 4 + 2][k] = (unsigned short)(p >> 16);
            p = split_bf16(v.w); Bhi[q * 4 + 3][k] = (unsigned short)p; Blo[q * 4 + 3][k] = (unsigned short)(p >> 16);
        }
        __syncthreads();

        // ---- fragments + MFMA ----
        bf16x8 ah[FR], al[FR], bh[FC], bl[FC];
        #pragma unroll
        for (int r = 0; r < FR; ++r) {
            ah[r] = __builtin_bit_cast(bf16x8, *(const u16x8*)&Ahi[r0 + r * 16 + l15][kof]);
            al[r] = __builtin_bit_cast(bf16x8, *(const u16x8*)&Alo[r0 + r * 16 + l15][kof]);
        }
        #pragma unroll
        for (int c = 0; c < FC; ++c) {
            bh[c] = __builtin_bit_cast(bf16x8, *(const u16x8*)&Bhi[c0 + c * 16 + l15][kof]);
            bl[c] = __builtin_bit_cast(bf16x8, *(const u16x8*)&Blo[c0 + c * 16 + l15][kof]);
        }
        #pragma unroll
        for (int r = 0; r < FR; ++r)
            #pragma unroll
            for (int c = 0; c < FC; ++c) {
                acc[r][c] = __builtin_amdgcn_mfma_f32_16x16x32_bf16(ah[r], bh[c], acc[r][c], 0, 0, 0);
                acc[r][c] = __builtin_amdgcn_mfma_f32_16x16x32_bf16(ah[r], bl[c], acc[r][c], 0, 0, 0);
                acc[r][c] = __builtin_amdgcn_mfma_f32_16x16x32_bf16(al[r], bh[c], acc[r][c], 0, 0, 0);
            }
        __syncthreads();
    }

    // ---- epilogue: C/D frag layout col=lane&15, row=(lane>>4)*4+reg ----
    #pragma unroll
    for (int r = 0; r < FR; ++r) {
        #pragma unroll
        for (int j = 0; j < 4; ++j) {
            int gr = row0 + r0 + r * 16 + (lane >> 4) * 4 + j;
            if (gr >= N_NODES) continue;
            float s = dinv[gr];
            #pragma unroll
            for (int c = 0; c < FC; ++c)
                C[(size_t)gr * M + c0 + c * 16 + l15] = acc[r][c][j] * s;
        }
    }
}

// ---------------- CSR gather: out[n] = dinv[n]*(sum hs[src] + hs[n]) + b ----------------
template<int M, int G>
__global__ __launch_bounds__(256) void gather_kernel(const int* __restrict__ rowptr,
                                                     const int* __restrict__ esorted,
                                                     const float* __restrict__ dinv,
                                                     const float* __restrict__ hs,
                                                     const float* __restrict__ bias,
                                                     float* __restrict__ out) {
    static_assert(M == 2 * G, "layout");
    int gid = blockIdx.x * blockDim.x + threadIdx.x;
    int node = gid / G;
    int lane = gid % G;
    if (node >= N_NODES) return;
    int beg = rowptr[node], end = rowptr[node + 1];
    float dn = dinv[node];
    const float2* hp = (const float2*)hs;
    float2 acc = hp[(size_t)node * G + lane];   // self term (hs[n])
    int j = beg;
    for (; j + 4 <= end; j += 4) {
        int s0 = esorted[j + 0];
        int s1 = esorted[j + 1];
        int s2 = esorted[j + 2];
        int s3 = esorted[j + 3];
        float2 v0 = hp[(size_t)s0 * G + lane];
        float2 v1 = hp[(size_t)s1 * G + lane];
        float2 v2 = hp[(size_t)s2 * G + lane];
        float2 v3 = hp[(size_t)s3 * G + lane];
        acc.x += (v0.x + v1.x) + (v2.x + v3.x);
        acc.y += (v0.y + v1.y) + (v2.y + v3.y);
    }
    for (; j < end; ++j) {
        int s = esorted[j];
        float2 v = hp[(size_t)s * G + lane];
        acc.x += v.x;
        acc.y += v.y;
    }
    float2 b = ((const float2*)bias)[lane];
    float2 o;
    o.x = acc.x * dn + b.x;
    o.y = acc.y * dn + b.y;
    ((float2*)out)[(size_t)node * G + lane] = o;
}

// ---------------- log_softmax over 32 classes ----------------
__global__ void log_softmax32_kernel(const float* __restrict__ in, float* __restrict__ out) {
    int t = blockIdx.x * blockDim.x + threadIdx.x;
    int row = t >> 5;
    if (row >= N_NODES) return;
    float v = in[t];
    float m = v;
    #pragma unroll
    for (int o = 16; o; o >>= 1) m = fmaxf(m, __shfl_xor(m, o, 32));
    float e = expf(v - m);
    float s = e;
    #pragma unroll
    for (int o = 16; o; o >>= 1) s += __shfl_xor(s, o, 32);
    out[t] = v - m - logf(s);
}

extern "C" void kernel_launch(void* const* d_in, const int* in_sizes, int n_in,
                              void* d_out, int out_size, void* d_ws, size_t ws_size,
                              hipStream_t stream) {
    const float* x  = (const float*)d_in[0];
    const int*   ei = (const int*)d_in[1];     // [2, E] int32
    const float* W0 = (const float*)d_in[2];
    const float* b0 = (const float*)d_in[3];
    const float* W1 = (const float*)d_in[4];
    const float* b1 = (const float*)d_in[5];
    const float* W2 = (const float*)d_in[6];
    const float* b2 = (const float*)d_in[7];
    float* out = (float*)d_out;

    char* ws = (char*)d_ws;
    float* dinv    = (float*)(ws + 0);                  // 400 KB
    int*   deg     = (int*)  (ws + (512 << 10));        // 400 KB (reused as cursor)
    int*   rowptr  = (int*)  (ws + (1 << 20));          // 400 KB + 4
    int*   bsums   = (int*)  (ws + (1536 << 10));       // ~1.6 KB
    int*   esorted = (int*)  (ws + (2 << 20));          // 6.4 MB
    float* bufA    = (float*)(ws + 9437184);            // 51.2 MB
    float* bufB    = (float*)(ws + 9437184 + 51200000); // 51.2 MB
    const int* esrc = ei;
    const int* edst = ei + N_EDGES;

    const int NB = (N_NODES + 255) / 256;   // 391

    // ---- degree / dinv / CSR ----
    (void)hipMemsetAsync(deg, 0, N_NODES * sizeof(int), stream);
    count_deg_kernel<<<N_EDGES / 256, 256, 0, stream>>>(edst, deg);
    dinv_kernel<<<NB, 256, 0, stream>>>(deg, dinv);
    block_scan_kernel<<<NB, 256, 0, stream>>>(deg, rowptr, bsums);
    scan_bsums_kernel<<<1, 512, 0, stream>>>(bsums, NB);
    add_offsets_kernel<<<NB, 256, 0, stream>>>(rowptr, bsums, deg /*cursor*/);
    fill_kernel<<<N_EDGES / 256, 256, 0, stream>>>(esrc, edst, deg /*cursor*/, esorted);

    const int RB128 = (N_NODES + 127) / 128;   // 782

    // ---- layer 0: hs = (x @ W0) * dinv ; aggregate ----
    mfma_gemm_kernel<256, 128, 2, 2><<<dim3(1, RB128), 256, 0, stream>>>(x, W0, dinv, bufA);
    gather_kernel<128, 64><<<(N_NODES * 64 + 255) / 256, 256, 0, stream>>>(
        rowptr, esorted, dinv, bufA, b0, bufB);

    // ---- layer 1 ----
    mfma_gemm_kernel<128, 128, 2, 2><<<dim3(1, RB128), 256, 0, stream>>>(bufB, W1, dinv, bufA);
    gather_kernel<128, 64><<<(N_NODES * 64 + 255) / 256, 256, 0, stream>>>(
        rowptr, esorted, dinv, bufA, b1, bufB);

    // ---- layer 2 ----
    mfma_gemm_kernel<128, 32, 4, 1><<<dim3(1, RB128), 256, 0, stream>>>(bufB, W2, dinv, bufA);
    gather_kernel<32, 16><<<(N_NODES * 16 + 255) / 256, 256, 0, stream>>>(
        rowptr, esorted, dinv, bufA, b2, bufB);

    // ---- log_softmax ----
    log_softmax32_kernel<<<N_NODES * 32 / 256 + 1, 256, 0, stream>>>(bufB, out);
}

// Round 6
// 528.270 us; speedup vs baseline: 11.9916x; 1.2069x over previous
//
#include <hip/hip_runtime.h>
#include <hip/hip_bf16.h>

#define N_NODES 100000
#define N_EDGES 1600000

typedef __bf16 bf16x8 __attribute__((ext_vector_type(8)));
typedef float f32x4 __attribute__((ext_vector_type(4)));
typedef unsigned short u16x8 __attribute__((ext_vector_type(8)));
typedef unsigned short u16x4 __attribute__((ext_vector_type(4)));
typedef _Float16 f16x4 __attribute__((ext_vector_type(4)));

// ---------------- degree count (in-degree at dst) ----------------
__global__ void count_deg_kernel(const int* __restrict__ dst, int* __restrict__ deg) {
    int i = blockIdx.x * blockDim.x + threadIdx.x;
    if (i < N_EDGES) atomicAdd(&deg[dst[i]], 1);
}

__global__ void dinv_kernel(const int* __restrict__ deg, float* __restrict__ dinv) {
    int i = blockIdx.x * blockDim.x + threadIdx.x;
    if (i < N_NODES) dinv[i] = 1.0f / sqrtf((float)deg[i] + 1.0f);
}

// ---------------- CSR build: block scan -> partial scan -> add ----------------
__global__ void block_scan_kernel(const int* __restrict__ deg, int* __restrict__ rowptr,
                                  int* __restrict__ bsums) {
    __shared__ int s[256];
    int i = blockIdx.x * 256 + threadIdx.x;
    int v = (i < N_NODES) ? deg[i] : 0;
    s[threadIdx.x] = v;
    __syncthreads();
    #pragma unroll
    for (int off = 1; off < 256; off <<= 1) {
        int t = (threadIdx.x >= off) ? s[threadIdx.x - off] : 0;
        __syncthreads();
        s[threadIdx.x] += t;
        __syncthreads();
    }
    if (i < N_NODES) rowptr[i] = s[threadIdx.x] - v;   // exclusive within block
    if (threadIdx.x == 255) bsums[blockIdx.x] = s[255];
}

__global__ void scan_bsums_kernel(int* __restrict__ bsums, int nB) {
    __shared__ int s[512];
    int tid = threadIdx.x;
    int v = (tid < nB) ? bsums[tid] : 0;
    s[tid] = v;
    __syncthreads();
    #pragma unroll
    for (int off = 1; off < 512; off <<= 1) {
        int t = (tid >= off) ? s[tid - off] : 0;
        __syncthreads();
        s[tid] += t;
        __syncthreads();
    }
    if (tid < nB) bsums[tid] = s[tid] - v;             // exclusive
}

__global__ void add_offsets_kernel(int* __restrict__ rowptr, const int* __restrict__ bsums,
                                   int* __restrict__ cursor) {
    int i = blockIdx.x * 256 + threadIdx.x;
    if (i < N_NODES) {
        int r = rowptr[i] + bsums[blockIdx.x];
        rowptr[i] = r;
        cursor[i] = r;
    }
    if (i == 0) rowptr[N_NODES] = N_EDGES;
}

__global__ void fill_kernel(const int* __restrict__ esrc, const int* __restrict__ edst,
                            int* __restrict__ cursor, int* __restrict__ esorted) {
    int e = blockIdx.x * 256 + threadIdx.x;
    if (e < N_EDGES) {
        int pos = atomicAdd(&cursor[edst[e]], 1);
        esorted[pos] = esrc[e];
    }
}

// ---------------- MFMA GEMM (bf16x2 split emulating fp32) ----------------
// C[r,:] = fp16( (A @ W)[r,:] * dinv[r] ), via Ahi@Whi + Ahi@Wlo + Alo@Whi
// returns hi in bits[15:0], lo in bits[31:16]
__device__ inline unsigned int split_bf16(float v) {
    __bf16 h = (__bf16)v;
    float r = v - (float)h;
    __bf16 l = (__bf16)r;
    unsigned int hu = __builtin_bit_cast(unsigned short, h);
    unsigned int lu = __builtin_bit_cast(unsigned short, l);
    return hu | (lu << 16);
}

template<int K, int M, int WR, int WC>
__global__ __launch_bounds__(256) void mfma_gemm_kernel(const float* __restrict__ A,
                                                        const float* __restrict__ W,
                                                        const float* __restrict__ dinv,
                                                        _Float16* __restrict__ C) {
    constexpr int BM = 128;
    constexpr int FR = BM / (WR * 16);     // row frags per wave
    constexpr int FC = M / (WC * 16);      // col frags per wave
    constexpr int LD = 40;                 // padded k-stride (ushorts): 80B rows, 16B-aligned
    __shared__ unsigned short Ahi[BM][LD], Alo[BM][LD];
    __shared__ unsigned short Bhi[M][LD],  Blo[M][LD];   // W transposed: [col][k]

    const int tid = threadIdx.x;
    const int row0 = blockIdx.y * BM;
    const int wave = tid >> 6, lane = tid & 63;
    const int wr = wave / WC, wc = wave % WC;
    const int r0 = wr * FR * 16, c0 = wc * FC * 16;
    const int l15 = lane & 15, kof = (lane >> 4) * 8;

    f32x4 acc[FR][FC] = {};

    for (int k0 = 0; k0 < K; k0 += 32) {
        // ---- stage A tile: BM x 32 fp32 -> hi/lo bf16 ----
        #pragma unroll
        for (int i = tid; i < BM * 8; i += 256) {
            int row = i >> 3, q = i & 7;            // q*4 = k offset
            int gr = row0 + row; if (gr >= N_NODES) gr = N_NODES - 1;
            float4 v = *(const float4*)&A[(size_t)gr * K + k0 + q * 4];
            unsigned int p0 = split_bf16(v.x);
            unsigned int p1 = split_bf16(v.y);
            unsigned int p2 = split_bf16(v.z);
            unsigned int p3 = split_bf16(v.w);
            u16x4 h4, l4;
            h4[0] = (unsigned short)p0; l4[0] = (unsigned short)(p0 >> 16);
            h4[1] = (unsigned short)p1; l4[1] = (unsigned short)(p1 >> 16);
            h4[2] = (unsigned short)p2; l4[2] = (unsigned short)(p2 >> 16);
            h4[3] = (unsigned short)p3; l4[3] = (unsigned short)(p3 >> 16);
            *(u16x4*)&Ahi[row][q * 4] = h4;
            *(u16x4*)&Alo[row][q * 4] = l4;
        }
        // ---- stage W tile: 32 x M fp32 -> transposed hi/lo bf16 ----
        constexpr int BQ = M / 4;
        #pragma unroll
        for (int i = tid; i < 32 * BQ; i += 256) {
            int k = i / BQ, q = i % BQ;
            float4 v = *(const float4*)&W[(size_t)(k0 + k) * M + q * 4];
            unsigned int p;
            p = split_bf16(v.x); Bhi[q * 4 + 0][k] = (unsigned short)p; Blo[q * 4 + 0][k] = (unsigned short)(p >> 16);
            p = split_bf16(v.y); Bhi[q * 4 + 1][k] = (unsigned short)p; Blo[q * 4 + 1][k] = (unsigned short)(p >> 16);
            p = split_bf16(v.z); Bhi[q * 4 + 2][k] = (unsigned short)p; Blo[q * 4 + 2][k] = (unsigned short)(p >> 16);
            p = split_bf16(v.w); Bhi[q * 4 + 3][k] = (unsigned short)p; Blo[q * 4 + 3][k] = (unsigned short)(p >> 16);
        }
        __syncthreads();

        // ---- fragments + MFMA ----
        bf16x8 ah[FR], al[FR], bh[FC], bl[FC];
        #pragma unroll
        for (int r = 0; r < FR; ++r) {
            ah[r] = __builtin_bit_cast(bf16x8, *(const u16x8*)&Ahi[r0 + r * 16 + l15][kof]);
            al[r] = __builtin_bit_cast(bf16x8, *(const u16x8*)&Alo[r0 + r * 16 + l15][kof]);
        }
        #pragma unroll
        for (int c = 0; c < FC; ++c) {
            bh[c] = __builtin_bit_cast(bf16x8, *(const u16x8*)&Bhi[c0 + c * 16 + l15][kof]);
            bl[c] = __builtin_bit_cast(bf16x8, *(const u16x8*)&Blo[c0 + c * 16 + l15][kof]);
        }
        #pragma unroll
        for (int r = 0; r < FR; ++r)
            #pragma unroll
            for (int c = 0; c < FC; ++c) {
                acc[r][c] = __builtin_amdgcn_mfma_f32_16x16x32_bf16(ah[r], bh[c], acc[r][c], 0, 0, 0);
                acc[r][c] = __builtin_amdgcn_mfma_f32_16x16x32_bf16(ah[r], bl[c], acc[r][c], 0, 0, 0);
                acc[r][c] = __builtin_amdgcn_mfma_f32_16x16x32_bf16(al[r], bh[c], acc[r][c], 0, 0, 0);
            }
        __syncthreads();
    }

    // ---- epilogue: C/D frag layout col=lane&15, row=(lane>>4)*4+reg; fp16 store ----
    #pragma unroll
    for (int r = 0; r < FR; ++r) {
        #pragma unroll
        for (int j = 0; j < 4; ++j) {
            int gr = row0 + r0 + r * 16 + (lane >> 4) * 4 + j;
            if (gr >= N_NODES) continue;
            float s = dinv[gr];
            #pragma unroll
            for (int c = 0; c < FC; ++c)
                C[(size_t)gr * M + c0 + c * 16 + l15] = (_Float16)(acc[r][c][j] * s);
        }
    }
}

// ---------------- CSR gather: out[n] = dinv[n]*(sum hs16[src] + hs16[n]) + b ----------------
// G lanes per node, each lane owns one f16x4 chunk (M == 4*G); fp32 accumulate
template<int M, int G>
__global__ __launch_bounds__(256) void gather_kernel(const int* __restrict__ rowptr,
                                                     const int* __restrict__ esorted,
                                                     const float* __restrict__ dinv,
                                                     const f16x4* __restrict__ hs,
                                                     const float* __restrict__ bias,
                                                     float* __restrict__ out) {
    static_assert(M == 4 * G, "layout");
    constexpr int R = M / 4;   // f16x4 chunks per row
    int gid = blockIdx.x * blockDim.x + threadIdx.x;
    int node = gid / G;
    int lane = gid % G;
    if (node >= N_NODES) return;
    int beg = rowptr[node], end = rowptr[node + 1];
    float dn = dinv[node];
    f16x4 hv = hs[(size_t)node * R + lane];   // self term
    float4 acc = make_float4((float)hv[0], (float)hv[1], (float)hv[2], (float)hv[3]);
    int j = beg;
    for (; j + 4 <= end; j += 4) {
        int s0 = esorted[j + 0];
        int s1 = esorted[j + 1];
        int s2 = esorted[j + 2];
        int s3 = esorted[j + 3];
        f16x4 v0 = hs[(size_t)s0 * R + lane];
        f16x4 v1 = hs[(size_t)s1 * R + lane];
        f16x4 v2 = hs[(size_t)s2 * R + lane];
        f16x4 v3 = hs[(size_t)s3 * R + lane];
        acc.x += ((float)v0[0] + (float)v1[0]) + ((float)v2[0] + (float)v3[0]);
        acc.y += ((float)v0[1] + (float)v1[1]) + ((float)v2[1] + (float)v3[1]);
        acc.z += ((float)v0[2] + (float)v1[2]) + ((float)v2[2] + (float)v3[2]);
        acc.w += ((float)v0[3] + (float)v1[3]) + ((float)v2[3] + (float)v3[3]);
    }
    for (; j < end; ++j) {
        int s = esorted[j];
        f16x4 v = hs[(size_t)s * R + lane];
        acc.x += (float)v[0];
        acc.y += (float)v[1];
        acc.z += (float)v[2];
        acc.w += (float)v[3];
    }
    float4 b = ((const float4*)bias)[lane];
    float4 o;
    o.x = acc.x * dn + b.x;
    o.y = acc.y * dn + b.y;
    o.z = acc.z * dn + b.z;
    o.w = acc.w * dn + b.w;
    ((float4*)out)[(size_t)node * R + lane] = o;
}

// ---------------- log_softmax over 32 classes ----------------
__global__ void log_softmax32_kernel(const float* __restrict__ in, float* __restrict__ out) {
    int t = blockIdx.x * blockDim.x + threadIdx.x;
    int row = t >> 5;
    if (row >= N_NODES) return;
    float v = in[t];
    float m = v;
    #pragma unroll
    for (int o = 16; o; o >>= 1) m = fmaxf(m, __shfl_xor(m, o, 32));
    float e = expf(v - m);
    float s = e;
    #pragma unroll
    for (int o = 16; o; o >>= 1) s += __shfl_xor(s, o, 32);
    out[t] = v - m - logf(s);
}

extern "C" void kernel_launch(void* const* d_in, const int* in_sizes, int n_in,
                              void* d_out, int out_size, void* d_ws, size_t ws_size,
                              hipStream_t stream) {
    const float* x  = (const float*)d_in[0];
    const int*   ei = (const int*)d_in[1];     // [2, E] int32
    const float* W0 = (const float*)d_in[2];
    const float* b0 = (const float*)d_in[3];
    const float* W1 = (const float*)d_in[4];
    const float* b1 = (const float*)d_in[5];
    const float* W2 = (const float*)d_in[6];
    const float* b2 = (const float*)d_in[7];
    float* out = (float*)d_out;

    char* ws = (char*)d_ws;
    float* dinv    = (float*)(ws + 0);                  // 400 KB
    int*   deg     = (int*)  (ws + (512 << 10));        // 400 KB (reused as cursor)
    int*   rowptr  = (int*)  (ws + (1 << 20));          // 400 KB + 4
    int*   bsums   = (int*)  (ws + (1536 << 10));       // ~1.6 KB
    int*   esorted = (int*)  (ws + (2 << 20));          // 6.4 MB
    _Float16* hs   = (_Float16*)(ws + 9437184);         // 25.6 MB (fp16 h*dinv)
    float* bufB    = (float*)(ws + 9437184 + 51200000); // 51.2 MB (layer outputs, fp32)
    const int* esrc = ei;
    const int* edst = ei + N_EDGES;

    const int NB = (N_NODES + 255) / 256;   // 391

    // ---- degree / dinv / CSR ----
    (void)hipMemsetAsync(deg, 0, N_NODES * sizeof(int), stream);
    count_deg_kernel<<<N_EDGES / 256, 256, 0, stream>>>(edst, deg);
    dinv_kernel<<<NB, 256, 0, stream>>>(deg, dinv);
    block_scan_kernel<<<NB, 256, 0, stream>>>(deg, rowptr, bsums);
    scan_bsums_kernel<<<1, 512, 0, stream>>>(bsums, NB);
    add_offsets_kernel<<<NB, 256, 0, stream>>>(rowptr, bsums, deg /*cursor*/);
    fill_kernel<<<N_EDGES / 256, 256, 0, stream>>>(esrc, edst, deg /*cursor*/, esorted);

    const int RB128 = (N_NODES + 127) / 128;   // 782

    // ---- layer 0: hs = fp16((x @ W0) * dinv) ; aggregate ----
    mfma_gemm_kernel<256, 128, 2, 2><<<dim3(1, RB128), 256, 0, stream>>>(x, W0, dinv, hs);
    gather_kernel<128, 32><<<(N_NODES * 32 + 255) / 256, 256, 0, stream>>>(
        rowptr, esorted, dinv, (const f16x4*)hs, b0, bufB);

    // ---- layer 1 ----
    mfma_gemm_kernel<128, 128, 2, 2><<<dim3(1, RB128), 256, 0, stream>>>(bufB, W1, dinv, hs);
    gather_kernel<128, 32><<<(N_NODES * 32 + 255) / 256, 256, 0, stream>>>(
        rowptr, esorted, dinv, (const f16x4*)hs, b1, bufB);

    // ---- layer 2 ----
    mfma_gemm_kernel<128, 32, 4, 1><<<dim3(1, RB128), 256, 0, stream>>>(bufB, W2, dinv, hs);
    gather_kernel<32, 8><<<(N_NODES * 8 + 255) / 256, 256, 0, stream>>>(
        rowptr, esorted, dinv, (const f16x4*)hs, b2, bufB);

    // ---- log_softmax ----
    log_softmax32_kernel<<<N_NODES * 32 / 256 + 1, 256, 0, stream>>>(bufB, out);
}

// Round 7
// 463.220 us; speedup vs baseline: 13.6755x; 1.1404x over previous
//
#include <hip/hip_runtime.h>
#include <hip/hip_bf16.h>

#define N_NODES 100000
#define N_EDGES 1600000
#define SLICE_N 12500   // N_NODES / 8 dst-slices for XCD-local fill

typedef __bf16 bf16x8 __attribute__((ext_vector_type(8)));
typedef float f32x4 __attribute__((ext_vector_type(4)));
typedef unsigned short u16x8 __attribute__((ext_vector_type(8)));
typedef unsigned short u16x4 __attribute__((ext_vector_type(4)));
typedef _Float16 f16x4 __attribute__((ext_vector_type(4)));

// ---------------- degree count (in-degree at dst) ----------------
__global__ void count_deg_kernel(const int* __restrict__ dst, int* __restrict__ deg) {
    int i = blockIdx.x * blockDim.x + threadIdx.x;
    if (i < N_EDGES) atomicAdd(&deg[dst[i]], 1);
}

__global__ void dinv_kernel(const int* __restrict__ deg, float* __restrict__ dinv) {
    int i = blockIdx.x * blockDim.x + threadIdx.x;
    if (i < N_NODES) dinv[i] = 1.0f / sqrtf((float)deg[i] + 1.0f);
}

// ---------------- CSR build: block scan -> partial scan -> add ----------------
__global__ void block_scan_kernel(const int* __restrict__ deg, int* __restrict__ rowptr,
                                  int* __restrict__ bsums) {
    __shared__ int s[256];
    int i = blockIdx.x * 256 + threadIdx.x;
    int v = (i < N_NODES) ? deg[i] : 0;
    s[threadIdx.x] = v;
    __syncthreads();
    #pragma unroll
    for (int off = 1; off < 256; off <<= 1) {
        int t = (threadIdx.x >= off) ? s[threadIdx.x - off] : 0;
        __syncthreads();
        s[threadIdx.x] += t;
        __syncthreads();
    }
    if (i < N_NODES) rowptr[i] = s[threadIdx.x] - v;   // exclusive within block
    if (threadIdx.x == 255) bsums[blockIdx.x] = s[255];
}

__global__ void scan_bsums_kernel(int* __restrict__ bsums, int nB) {
    __shared__ int s[512];
    int tid = threadIdx.x;
    int v = (tid < nB) ? bsums[tid] : 0;
    s[tid] = v;
    __syncthreads();
    #pragma unroll
    for (int off = 1; off < 512; off <<= 1) {
        int t = (tid >= off) ? s[tid - off] : 0;
        __syncthreads();
        s[tid] += t;
        __syncthreads();
    }
    if (tid < nB) bsums[tid] = s[tid] - v;             // exclusive
}

__global__ void add_offsets_kernel(int* __restrict__ rowptr, const int* __restrict__ bsums,
                                   int* __restrict__ cursor) {
    int i = blockIdx.x * 256 + threadIdx.x;
    if (i < N_NODES) {
        int r = rowptr[i] + bsums[blockIdx.x];
        rowptr[i] = r;
        cursor[i] = r;
    }
    if (i == 0) rowptr[N_NODES] = N_EDGES;
}

// dst-sliced CSR fill: block handles (slice = blk&7, chunk = blk>>3); writes land in an
// L2-resident 0.8 MB window per slice, lines fill completely before eviction.
__global__ __launch_bounds__(256) void fill_slice_kernel(const int* __restrict__ esrc,
                                                         const int* __restrict__ edst,
                                                         int* __restrict__ cursor,
                                                         int* __restrict__ esorted) {
    const int slice = blockIdx.x & 7;
    const int chunk = blockIdx.x >> 3;
    const int base = chunk * 2048 + threadIdx.x;
    const int lo = slice * SLICE_N, hi = lo + SLICE_N;
    #pragma unroll
    for (int i = 0; i < 8; ++i) {
        int e = base + i * 256;
        if (e < N_EDGES) {
            int d = edst[e];
            if (d >= lo && d < hi) {
                int pos = atomicAdd(&cursor[d], 1);
                esorted[pos] = esrc[e];
            }
        }
    }
}

// ---------------- MFMA GEMM (bf16x2 split emulating fp32) ----------------
// C[r,:] = fp16( (A @ W)[r,:] * dinv[r] ), via Ahi@Whi + Ahi@Wlo + Alo@Whi
__device__ inline unsigned int split_bf16(float v) {
    __bf16 h = (__bf16)v;
    float r = v - (float)h;
    __bf16 l = (__bf16)r;
    unsigned int hu = __builtin_bit_cast(unsigned short, h);
    unsigned int lu = __builtin_bit_cast(unsigned short, l);
    return hu | (lu << 16);
}

template<int K, int M, int WR, int WC>
__global__ __launch_bounds__(256) void mfma_gemm_kernel(const float* __restrict__ A,
                                                        const float* __restrict__ W,
                                                        const float* __restrict__ dinv,
                                                        _Float16* __restrict__ C) {
    constexpr int BM = 128;
    constexpr int FR = BM / (WR * 16);     // row frags per wave
    constexpr int FC = M / (WC * 16);      // col frags per wave
    constexpr int LD = 40;                 // padded k-stride (ushorts): 80B rows, 16B-aligned
    __shared__ unsigned short Ahi[BM][LD], Alo[BM][LD];
    __shared__ unsigned short Bhi[M][LD],  Blo[M][LD];   // W transposed: [col][k]

    const int tid = threadIdx.x;
    const int row0 = blockIdx.y * BM;
    const int wave = tid >> 6, lane = tid & 63;
    const int wr = wave / WC, wc = wave % WC;
    const int r0 = wr * FR * 16, c0 = wc * FC * 16;
    const int l15 = lane & 15, kof = (lane >> 4) * 8;

    f32x4 acc[FR][FC] = {};

    for (int k0 = 0; k0 < K; k0 += 32) {
        // ---- stage A tile: BM x 32 fp32 -> hi/lo bf16 ----
        #pragma unroll
        for (int i = tid; i < BM * 8; i += 256) {
            int row = i >> 3, q = i & 7;            // q*4 = k offset
            int gr = row0 + row; if (gr >= N_NODES) gr = N_NODES - 1;
            float4 v = *(const float4*)&A[(size_t)gr * K + k0 + q * 4];
            unsigned int p0 = split_bf16(v.x);
            unsigned int p1 = split_bf16(v.y);
            unsigned int p2 = split_bf16(v.z);
            unsigned int p3 = split_bf16(v.w);
            u16x4 h4, l4;
            h4[0] = (unsigned short)p0; l4[0] = (unsigned short)(p0 >> 16);
            h4[1] = (unsigned short)p1; l4[1] = (unsigned short)(p1 >> 16);
            h4[2] = (unsigned short)p2; l4[2] = (unsigned short)(p2 >> 16);
            h4[3] = (unsigned short)p3; l4[3] = (unsigned short)(p3 >> 16);
            *(u16x4*)&Ahi[row][q * 4] = h4;
            *(u16x4*)&Alo[row][q * 4] = l4;
        }
        // ---- stage W tile: 32 x M fp32 -> transposed hi/lo bf16 ----
        constexpr int BQ = M / 4;
        #pragma unroll
        for (int i = tid; i < 32 * BQ; i += 256) {
            int k = i / BQ, q = i % BQ;
            float4 v = *(const float4*)&W[(size_t)(k0 + k) * M + q * 4];
            unsigned int p;
            p = split_bf16(v.x); Bhi[q * 4 + 0][k] = (unsigned short)p; Blo[q * 4 + 0][k] = (unsigned short)(p >> 16);
            p = split_bf16(v.y); Bhi[q * 4 + 1][k] = (unsigned short)p; Blo[q * 4 + 1][k] = (unsigned short)(p >> 16);
            p = split_bf16(v.z); Bhi[q * 4 + 2][k] = (unsigned short)p; Blo[q * 4 + 2][k] = (unsigned short)(p >> 16);
            p = split_bf16(v.w); Bhi[q * 4 + 3][k] = (unsigned short)p; Blo[q * 4 + 3][k] = (unsigned short)(p >> 16);
        }
        __syncthreads();

        // ---- fragments + MFMA ----
        bf16x8 ah[FR], al[FR], bh[FC], bl[FC];
        #pragma unroll
        for (int r = 0; r < FR; ++r) {
            ah[r] = __builtin_bit_cast(bf16x8, *(const u16x8*)&Ahi[r0 + r * 16 + l15][kof]);
            al[r] = __builtin_bit_cast(bf16x8, *(const u16x8*)&Alo[r0 + r * 16 + l15][kof]);
        }
        #pragma unroll
        for (int c = 0; c < FC; ++c) {
            bh[c] = __builtin_bit_cast(bf16x8, *(const u16x8*)&Bhi[c0 + c * 16 + l15][kof]);
            bl[c] = __builtin_bit_cast(bf16x8, *(const u16x8*)&Blo[c0 + c * 16 + l15][kof]);
        }
        #pragma unroll
        for (int r = 0; r < FR; ++r)
            #pragma unroll
            for (int c = 0; c < FC; ++c) {
                acc[r][c] = __builtin_amdgcn_mfma_f32_16x16x32_bf16(ah[r], bh[c], acc[r][c], 0, 0, 0);
                acc[r][c] = __builtin_amdgcn_mfma_f32_16x16x32_bf16(ah[r], bl[c], acc[r][c], 0, 0, 0);
                acc[r][c] = __builtin_amdgcn_mfma_f32_16x16x32_bf16(al[r], bh[c], acc[r][c], 0, 0, 0);
            }
        __syncthreads();
    }

    // ---- epilogue: C/D frag layout col=lane&15, row=(lane>>4)*4+reg; fp16 store ----
    #pragma unroll
    for (int r = 0; r < FR; ++r) {
        #pragma unroll
        for (int j = 0; j < 4; ++j) {
            int gr = row0 + r0 + r * 16 + (lane >> 4) * 4 + j;
            if (gr >= N_NODES) continue;
            float s = dinv[gr];
            #pragma unroll
            for (int c = 0; c < FC; ++c)
                C[(size_t)gr * M + c0 + c * 16 + l15] = (_Float16)(acc[r][c][j] * s);
        }
    }
}

// ---------------- CSR gather: out[n] = dinv[n]*(sum hs16[src] + hs16[n]) + b ----------------
// G lanes per node, each lane owns one f16x4 chunk (M == 4*G); fp32 accumulate
template<int M, int G>
__global__ __launch_bounds__(256) void gather_kernel(const int* __restrict__ rowptr,
                                                     const int* __restrict__ esorted,
                                                     const float* __restrict__ dinv,
                                                     const f16x4* __restrict__ hs,
                                                     const float* __restrict__ bias,
                                                     float* __restrict__ out) {
    static_assert(M == 4 * G, "layout");
    constexpr int R = M / 4;   // f16x4 chunks per row
    int gid = blockIdx.x * blockDim.x + threadIdx.x;
    int node = gid / G;
    int lane = gid % G;
    if (node >= N_NODES) return;
    int beg = rowptr[node], end = rowptr[node + 1];
    float dn = dinv[node];
    f16x4 hv = hs[(size_t)node * R + lane];   // self term
    float4 acc = make_float4((float)hv[0], (float)hv[1], (float)hv[2], (float)hv[3]);
    int j = beg;
    for (; j + 4 <= end; j += 4) {
        int s0 = esorted[j + 0];
        int s1 = esorted[j + 1];
        int s2 = esorted[j + 2];
        int s3 = esorted[j + 3];
        f16x4 v0 = hs[(size_t)s0 * R + lane];
        f16x4 v1 = hs[(size_t)s1 * R + lane];
        f16x4 v2 = hs[(size_t)s2 * R + lane];
        f16x4 v3 = hs[(size_t)s3 * R + lane];
        acc.x += ((float)v0[0] + (float)v1[0]) + ((float)v2[0] + (float)v3[0]);
        acc.y += ((float)v0[1] + (float)v1[1]) + ((float)v2[1] + (float)v3[1]);
        acc.z += ((float)v0[2] + (float)v1[2]) + ((float)v2[2] + (float)v3[2]);
        acc.w += ((float)v0[3] + (float)v1[3]) + ((float)v2[3] + (float)v3[3]);
    }
    for (; j < end; ++j) {
        int s = esorted[j];
        f16x4 v = hs[(size_t)s * R + lane];
        acc.x += (float)v[0];
        acc.y += (float)v[1];
        acc.z += (float)v[2];
        acc.w += (float)v[3];
    }
    float4 b = ((const float4*)bias)[lane];
    float4 o;
    o.x = acc.x * dn + b.x;
    o.y = acc.y * dn + b.y;
    o.z = acc.z * dn + b.z;
    o.w = acc.w * dn + b.w;
    ((float4*)out)[(size_t)node * R + lane] = o;
}

// ---------------- layer-2 gather fused with log_softmax (M=32, G=8) ----------------
__global__ __launch_bounds__(256) void gather_lsm_kernel(const int* __restrict__ rowptr,
                                                         const int* __restrict__ esorted,
                                                         const float* __restrict__ dinv,
                                                         const f16x4* __restrict__ hs,
                                                         const float* __restrict__ bias,
                                                         float* __restrict__ out) {
    constexpr int R = 8;   // f16x4 chunks per 32-wide row
    int gid = blockIdx.x * blockDim.x + threadIdx.x;
    int node = gid / 8;
    int lane = gid % 8;
    if (node >= N_NODES) return;
    int beg = rowptr[node], end = rowptr[node + 1];
    float dn = dinv[node];
    f16x4 hv = hs[(size_t)node * R + lane];
    float4 acc = make_float4((float)hv[0], (float)hv[1], (float)hv[2], (float)hv[3]);
    int j = beg;
    for (; j + 4 <= end; j += 4) {
        int s0 = esorted[j + 0];
        int s1 = esorted[j + 1];
        int s2 = esorted[j + 2];
        int s3 = esorted[j + 3];
        f16x4 v0 = hs[(size_t)s0 * R + lane];
        f16x4 v1 = hs[(size_t)s1 * R + lane];
        f16x4 v2 = hs[(size_t)s2 * R + lane];
        f16x4 v3 = hs[(size_t)s3 * R + lane];
        acc.x += ((float)v0[0] + (float)v1[0]) + ((float)v2[0] + (float)v3[0]);
        acc.y += ((float)v0[1] + (float)v1[1]) + ((float)v2[1] + (float)v3[1]);
        acc.z += ((float)v0[2] + (float)v1[2]) + ((float)v2[2] + (float)v3[2]);
        acc.w += ((float)v0[3] + (float)v1[3]) + ((float)v2[3] + (float)v3[3]);
    }
    for (; j < end; ++j) {
        int s = esorted[j];
        f16x4 v = hs[(size_t)s * R + lane];
        acc.x += (float)v[0];
        acc.y += (float)v[1];
        acc.z += (float)v[2];
        acc.w += (float)v[3];
    }
    float4 b = ((const float4*)bias)[lane];
    float4 o;
    o.x = acc.x * dn + b.x;
    o.y = acc.y * dn + b.y;
    o.z = acc.z * dn + b.z;
    o.w = acc.w * dn + b.w;
    // log_softmax over the 32-class row (8 lanes x 4)
    float m = fmaxf(fmaxf(o.x, o.y), fmaxf(o.z, o.w));
    m = fmaxf(m, __shfl_xor(m, 1, 8));
    m = fmaxf(m, __shfl_xor(m, 2, 8));
    m = fmaxf(m, __shfl_xor(m, 4, 8));
    float s = expf(o.x - m) + expf(o.y - m) + expf(o.z - m) + expf(o.w - m);
    s += __shfl_xor(s, 1, 8);
    s += __shfl_xor(s, 2, 8);
    s += __shfl_xor(s, 4, 8);
    float ls = m + logf(s);
    float4 r;
    r.x = o.x - ls; r.y = o.y - ls; r.z = o.z - ls; r.w = o.w - ls;
    ((float4*)out)[(size_t)node * R + lane] = r;
}

extern "C" void kernel_launch(void* const* d_in, const int* in_sizes, int n_in,
                              void* d_out, int out_size, void* d_ws, size_t ws_size,
                              hipStream_t stream) {
    const float* x  = (const float*)d_in[0];
    const int*   ei = (const int*)d_in[1];     // [2, E] int32
    const float* W0 = (const float*)d_in[2];
    const float* b0 = (const float*)d_in[3];
    const float* W1 = (const float*)d_in[4];
    const float* b1 = (const float*)d_in[5];
    const float* W2 = (const float*)d_in[6];
    const float* b2 = (const float*)d_in[7];
    float* out = (float*)d_out;

    char* ws = (char*)d_ws;
    float* dinv    = (float*)(ws + 0);                  // 400 KB
    int*   deg     = (int*)  (ws + (512 << 10));        // 400 KB (reused as cursor)
    int*   rowptr  = (int*)  (ws + (1 << 20));          // 400 KB + 4
    int*   bsums   = (int*)  (ws + (1536 << 10));       // ~1.6 KB
    int*   esorted = (int*)  (ws + (2 << 20));          // 6.4 MB
    _Float16* hs   = (_Float16*)(ws + 9437184);         // 25.6 MB (fp16 h*dinv)
    float* bufB    = (float*)(ws + 9437184 + 51200000); // 51.2 MB (layer outputs, fp32)
    const int* esrc = ei;
    const int* edst = ei + N_EDGES;

    const int NB = (N_NODES + 255) / 256;   // 391

    // ---- degree / dinv / CSR ----
    (void)hipMemsetAsync(deg, 0, N_NODES * sizeof(int), stream);
    count_deg_kernel<<<N_EDGES / 256, 256, 0, stream>>>(edst, deg);
    dinv_kernel<<<NB, 256, 0, stream>>>(deg, dinv);
    block_scan_kernel<<<NB, 256, 0, stream>>>(deg, rowptr, bsums);
    scan_bsums_kernel<<<1, 512, 0, stream>>>(bsums, NB);
    add_offsets_kernel<<<NB, 256, 0, stream>>>(rowptr, bsums, deg /*cursor*/);
    {
        const int chunks = (N_EDGES + 2047) / 2048;   // 782
        fill_slice_kernel<<<chunks * 8, 256, 0, stream>>>(esrc, edst, deg /*cursor*/, esorted);
    }

    const int RB128 = (N_NODES + 127) / 128;   // 782

    // ---- layer 0: hs = fp16((x @ W0) * dinv) ; aggregate ----
    mfma_gemm_kernel<256, 128, 2, 2><<<dim3(1, RB128), 256, 0, stream>>>(x, W0, dinv, hs);
    gather_kernel<128, 32><<<(N_NODES * 32 + 255) / 256, 256, 0, stream>>>(
        rowptr, esorted, dinv, (const f16x4*)hs, b0, bufB);

    // ---- layer 1 ----
    mfma_gemm_kernel<128, 128, 2, 2><<<dim3(1, RB128), 256, 0, stream>>>(bufB, W1, dinv, hs);
    gather_kernel<128, 32><<<(N_NODES * 32 + 255) / 256, 256, 0, stream>>>(
        rowptr, esorted, dinv, (const f16x4*)hs, b1, bufB);

    // ---- layer 2: gather fused with log_softmax, writes d_out ----
    mfma_gemm_kernel<128, 32, 4, 1><<<dim3(1, RB128), 256, 0, stream>>>(bufB, W2, dinv, hs);
    gather_lsm_kernel<<<(N_NODES * 8 + 255) / 256, 256, 0, stream>>>(
        rowptr, esorted, dinv, (const f16x4*)hs, b2, out);
}

// Round 8
// 456.257 us; speedup vs baseline: 13.8842x; 1.0153x over previous
//
#include <hip/hip_runtime.h>
#include <hip/hip_bf16.h>

#define N_NODES 100000
#define N_EDGES 1600000
#define SLICE_N 12500   // N_NODES / 8 dst-slices for XCD-local fill

typedef __bf16 bf16x8 __attribute__((ext_vector_type(8)));
typedef float f32x4 __attribute__((ext_vector_type(4)));
typedef unsigned short u16x8 __attribute__((ext_vector_type(8)));
typedef _Float16 f16x4 __attribute__((ext_vector_type(4)));

// ---------------- degree count (in-degree at dst) ----------------
__global__ void count_deg_kernel(const int* __restrict__ dst, int* __restrict__ deg) {
    int i = blockIdx.x * blockDim.x + threadIdx.x;
    if (i < N_EDGES) atomicAdd(&deg[dst[i]], 1);
}

__global__ void dinv_kernel(const int* __restrict__ deg, float* __restrict__ dinv) {
    int i = blockIdx.x * blockDim.x + threadIdx.x;
    if (i < N_NODES) dinv[i] = 1.0f / sqrtf((float)deg[i] + 1.0f);
}

// ---------------- CSR build: block scan -> partial scan -> add ----------------
__global__ void block_scan_kernel(const int* __restrict__ deg, int* __restrict__ rowptr,
                                  int* __restrict__ bsums) {
    __shared__ int s[256];
    int i = blockIdx.x * 256 + threadIdx.x;
    int v = (i < N_NODES) ? deg[i] : 0;
    s[threadIdx.x] = v;
    __syncthreads();
    #pragma unroll
    for (int off = 1; off < 256; off <<= 1) {
        int t = (threadIdx.x >= off) ? s[threadIdx.x - off] : 0;
        __syncthreads();
        s[threadIdx.x] += t;
        __syncthreads();
    }
    if (i < N_NODES) rowptr[i] = s[threadIdx.x] - v;   // exclusive within block
    if (threadIdx.x == 255) bsums[blockIdx.x] = s[255];
}

__global__ void scan_bsums_kernel(int* __restrict__ bsums, int nB) {
    __shared__ int s[512];
    int tid = threadIdx.x;
    int v = (tid < nB) ? bsums[tid] : 0;
    s[tid] = v;
    __syncthreads();
    #pragma unroll
    for (int off = 1; off < 512; off <<= 1) {
        int t = (tid >= off) ? s[tid - off] : 0;
        __syncthreads();
        s[tid] += t;
        __syncthreads();
    }
    if (tid < nB) bsums[tid] = s[tid] - v;             // exclusive
}

__global__ void add_offsets_kernel(int* __restrict__ rowptr, const int* __restrict__ bsums,
                                   int* __restrict__ cursor) {
    int i = blockIdx.x * 256 + threadIdx.x;
    if (i < N_NODES) {
        int r = rowptr[i] + bsums[blockIdx.x];
        rowptr[i] = r;
        cursor[i] = r;
    }
    if (i == 0) rowptr[N_NODES] = N_EDGES;
}

// dst-sliced CSR fill: block handles (slice = blk&7, chunk = blk>>3)
__global__ __launch_bounds__(256) void fill_slice_kernel(const int* __restrict__ esrc,
                                                         const int* __restrict__ edst,
                                                         int* __restrict__ cursor,
                                                         int* __restrict__ esorted) {
    const int slice = blockIdx.x & 7;
    const int chunk = blockIdx.x >> 3;
    const int base = chunk * 2048 + threadIdx.x;
    const int lo = slice * SLICE_N, hi = lo + SLICE_N;
    #pragma unroll
    for (int i = 0; i < 8; ++i) {
        int e = base + i * 256;
        if (e < N_EDGES) {
            int d = edst[e];
            if (d >= lo && d < hi) {
                int pos = atomicAdd(&cursor[d], 1);
                esorted[pos] = esrc[e];
            }
        }
    }
}

// ---------------- fp32 -> hi/lo bf16 split ----------------
// returns hi in bits[15:0], lo in bits[31:16]
__device__ inline unsigned int split_bf16(float v) {
    __bf16 h = (__bf16)v;
    float r = v - (float)h;
    __bf16 l = (__bf16)r;
    unsigned int hu = __builtin_bit_cast(unsigned short, h);
    unsigned int lu = __builtin_bit_cast(unsigned short, l);
    return hu | (lu << 16);
}

// W[K][M] row-major -> Wh/Wl[M][K] transposed bf16 hi/lo
__global__ void wsplit_kernel(const float* __restrict__ W, int K, int M,
                              unsigned short* __restrict__ Wh, unsigned short* __restrict__ Wl) {
    int i = blockIdx.x * 256 + threadIdx.x;
    if (i >= K * M) return;
    int k = i / M, col = i % M;
    unsigned int p = split_bf16(W[i]);
    Wh[col * K + k] = (unsigned short)p;
    Wl[col * K + k] = (unsigned short)(p >> 16);
}

// ---------------- LDS-free MFMA GEMM (bf16x2 split emulating fp32) ----------------
// C[r,:] = fp16( (A @ W)[r,:] * dinv[r] ) via Ahi@Whi + Ahi@Wlo + Alo@Whi.
// A fp32 loaded straight to registers and split in-register; W pre-split in global.
// 4 waves, each owns a 32-row strip (FR=2) and all M columns (FC=M/16).
template<int K, int M>
__global__ __launch_bounds__(256) void mfma_gemm_kernel(const float* __restrict__ A,
                                                        const unsigned short* __restrict__ Bh,
                                                        const unsigned short* __restrict__ Bl,
                                                        const float* __restrict__ dinv,
                                                        _Float16* __restrict__ C) {
    constexpr int BM = 128;
    constexpr int FR = 2;          // 2 row-frags (32 rows) per wave
    constexpr int FC = M / 16;     // all col-frags per wave
    const int tid = threadIdx.x;
    const int wave = tid >> 6, lane = tid & 63;
    const int row0 = blockIdx.x * BM;
    const int r0 = wave * FR * 16;
    const int l15 = lane & 15, kof = (lane >> 4) * 8;

    f32x4 acc[FR][FC] = {};

    #pragma unroll 2
    for (int k0 = 0; k0 < K; k0 += 32) {
        // ---- A fragments: fp32 global -> registers -> hi/lo bf16 ----
        bf16x8 ah[FR], al[FR];
        #pragma unroll
        for (int r = 0; r < FR; ++r) {
            int gr = row0 + r0 + r * 16 + l15;
            if (gr >= N_NODES) gr = N_NODES - 1;
            const float* ap = A + (size_t)gr * K + k0 + kof;
            f32x4 u0 = *(const f32x4*)ap;
            f32x4 u1 = *(const f32x4*)(ap + 4);
            u16x8 h8, l8;
            #pragma unroll
            for (int j = 0; j < 4; ++j) {
                unsigned int p0 = split_bf16(u0[j]);
                unsigned int p1 = split_bf16(u1[j]);
                h8[j] = (unsigned short)p0;     l8[j] = (unsigned short)(p0 >> 16);
                h8[4 + j] = (unsigned short)p1; l8[4 + j] = (unsigned short)(p1 >> 16);
            }
            ah[r] = __builtin_bit_cast(bf16x8, h8);
            al[r] = __builtin_bit_cast(bf16x8, l8);
        }
        // ---- B fragments: pre-split bf16 global (L1/L2-resident) ----
        bf16x8 bh[FC], bl[FC];
        #pragma unroll
        for (int c = 0; c < FC; ++c) {
            size_t boff = (size_t)(c * 16 + l15) * K + k0 + kof;
            bh[c] = __builtin_bit_cast(bf16x8, *(const u16x8*)(Bh + boff));
            bl[c] = __builtin_bit_cast(bf16x8, *(const u16x8*)(Bl + boff));
        }
        #pragma unroll
        for (int r = 0; r < FR; ++r)
            #pragma unroll
            for (int c = 0; c < FC; ++c) {
                acc[r][c] = __builtin_amdgcn_mfma_f32_16x16x32_bf16(ah[r], bh[c], acc[r][c], 0, 0, 0);
                acc[r][c] = __builtin_amdgcn_mfma_f32_16x16x32_bf16(ah[r], bl[c], acc[r][c], 0, 0, 0);
                acc[r][c] = __builtin_amdgcn_mfma_f32_16x16x32_bf16(al[r], bh[c], acc[r][c], 0, 0, 0);
            }
    }

    // ---- epilogue: C/D frag layout col=lane&15, row=(lane>>4)*4+reg; fp16 store ----
    #pragma unroll
    for (int r = 0; r < FR; ++r) {
        #pragma unroll
        for (int j = 0; j < 4; ++j) {
            int gr = row0 + r0 + r * 16 + (lane >> 4) * 4 + j;
            if (gr >= N_NODES) continue;
            float s = dinv[gr];
            #pragma unroll
            for (int c = 0; c < FC; ++c)
                C[(size_t)gr * M + c * 16 + l15] = (_Float16)(acc[r][c][j] * s);
        }
    }
}

// ---------------- CSR gather: out[n] = dinv[n]*(sum hs16[src] + hs16[n]) + b ----------------
template<int M, int G>
__global__ __launch_bounds__(256) void gather_kernel(const int* __restrict__ rowptr,
                                                     const int* __restrict__ esorted,
                                                     const float* __restrict__ dinv,
                                                     const f16x4* __restrict__ hs,
                                                     const float* __restrict__ bias,
                                                     float* __restrict__ out) {
    static_assert(M == 4 * G, "layout");
    constexpr int R = M / 4;   // f16x4 chunks per row
    int gid = blockIdx.x * blockDim.x + threadIdx.x;
    int node = gid / G;
    int lane = gid % G;
    if (node >= N_NODES) return;
    int beg = rowptr[node], end = rowptr[node + 1];
    float dn = dinv[node];
    f16x4 hv = hs[(size_t)node * R + lane];   // self term
    float4 acc = make_float4((float)hv[0], (float)hv[1], (float)hv[2], (float)hv[3]);
    int j = beg;
    for (; j + 4 <= end; j += 4) {
        int s0 = esorted[j + 0];
        int s1 = esorted[j + 1];
        int s2 = esorted[j + 2];
        int s3 = esorted[j + 3];
        f16x4 v0 = hs[(size_t)s0 * R + lane];
        f16x4 v1 = hs[(size_t)s1 * R + lane];
        f16x4 v2 = hs[(size_t)s2 * R + lane];
        f16x4 v3 = hs[(size_t)s3 * R + lane];
        acc.x += ((float)v0[0] + (float)v1[0]) + ((float)v2[0] + (float)v3[0]);
        acc.y += ((float)v0[1] + (float)v1[1]) + ((float)v2[1] + (float)v3[1]);
        acc.z += ((float)v0[2] + (float)v1[2]) + ((float)v2[2] + (float)v3[2]);
        acc.w += ((float)v0[3] + (float)v1[3]) + ((float)v2[3] + (float)v3[3]);
    }
    for (; j < end; ++j) {
        int s = esorted[j];
        f16x4 v = hs[(size_t)s * R + lane];
        acc.x += (float)v[0];
        acc.y += (float)v[1];
        acc.z += (float)v[2];
        acc.w += (float)v[3];
    }
    float4 b = ((const float4*)bias)[lane];
    float4 o;
    o.x = acc.x * dn + b.x;
    o.y = acc.y * dn + b.y;
    o.z = acc.z * dn + b.z;
    o.w = acc.w * dn + b.w;
    ((float4*)out)[(size_t)node * R + lane] = o;
}

// ---------------- layer-2 gather fused with log_softmax (M=32, G=8) ----------------
__global__ __launch_bounds__(256) void gather_lsm_kernel(const int* __restrict__ rowptr,
                                                         const int* __restrict__ esorted,
                                                         const float* __restrict__ dinv,
                                                         const f16x4* __restrict__ hs,
                                                         const float* __restrict__ bias,
                                                         float* __restrict__ out) {
    constexpr int R = 8;   // f16x4 chunks per 32-wide row
    int gid = blockIdx.x * blockDim.x + threadIdx.x;
    int node = gid / 8;
    int lane = gid % 8;
    if (node >= N_NODES) return;
    int beg = rowptr[node], end = rowptr[node + 1];
    float dn = dinv[node];
    f16x4 hv = hs[(size_t)node * R + lane];
    float4 acc = make_float4((float)hv[0], (float)hv[1], (float)hv[2], (float)hv[3]);
    int j = beg;
    for (; j + 4 <= end; j += 4) {
        int s0 = esorted[j + 0];
        int s1 = esorted[j + 1];
        int s2 = esorted[j + 2];
        int s3 = esorted[j + 3];
        f16x4 v0 = hs[(size_t)s0 * R + lane];
        f16x4 v1 = hs[(size_t)s1 * R + lane];
        f16x4 v2 = hs[(size_t)s2 * R + lane];
        f16x4 v3 = hs[(size_t)s3 * R + lane];
        acc.x += ((float)v0[0] + (float)v1[0]) + ((float)v2[0] + (float)v3[0]);
        acc.y += ((float)v0[1] + (float)v1[1]) + ((float)v2[1] + (float)v3[1]);
        acc.z += ((float)v0[2] + (float)v1[2]) + ((float)v2[2] + (float)v3[2]);
        acc.w += ((float)v0[3] + (float)v1[3]) + ((float)v2[3] + (float)v3[3]);
    }
    for (; j < end; ++j) {
        int s = esorted[j];
        f16x4 v = hs[(size_t)s * R + lane];
        acc.x += (float)v[0];
        acc.y += (float)v[1];
        acc.z += (float)v[2];
        acc.w += (float)v[3];
    }
    float4 b = ((const float4*)bias)[lane];
    float4 o;
    o.x = acc.x * dn + b.x;
    o.y = acc.y * dn + b.y;
    o.z = acc.z * dn + b.z;
    o.w = acc.w * dn + b.w;
    // log_softmax over the 32-class row (8 lanes x 4)
    float m = fmaxf(fmaxf(o.x, o.y), fmaxf(o.z, o.w));
    m = fmaxf(m, __shfl_xor(m, 1, 8));
    m = fmaxf(m, __shfl_xor(m, 2, 8));
    m = fmaxf(m, __shfl_xor(m, 4, 8));
    float s = expf(o.x - m) + expf(o.y - m) + expf(o.z - m) + expf(o.w - m);
    s += __shfl_xor(s, 1, 8);
    s += __shfl_xor(s, 2, 8);
    s += __shfl_xor(s, 4, 8);
    float ls = m + logf(s);
    float4 r;
    r.x = o.x - ls; r.y = o.y - ls; r.z = o.z - ls; r.w = o.w - ls;
    ((float4*)out)[(size_t)node * R + lane] = r;
}

extern "C" void kernel_launch(void* const* d_in, const int* in_sizes, int n_in,
                              void* d_out, int out_size, void* d_ws, size_t ws_size,
                              hipStream_t stream) {
    const float* x  = (const float*)d_in[0];
    const int*   ei = (const int*)d_in[1];     // [2, E] int32
    const float* W0 = (const float*)d_in[2];
    const float* b0 = (const float*)d_in[3];
    const float* W1 = (const float*)d_in[4];
    const float* b1 = (const float*)d_in[5];
    const float* W2 = (const float*)d_in[6];
    const float* b2 = (const float*)d_in[7];
    float* out = (float*)d_out;

    char* ws = (char*)d_ws;
    float* dinv    = (float*)(ws + 0);                  // 400 KB
    int*   deg     = (int*)  (ws + (512 << 10));        // 400 KB (reused as cursor)
    int*   rowptr  = (int*)  (ws + (1 << 20));          // 400 KB + 4
    int*   bsums   = (int*)  (ws + (1536 << 10));       // ~1.6 KB
    int*   esorted = (int*)  (ws + (2 << 20));          // 6.4 MB
    unsigned short* Wh0 = (unsigned short*)(ws + 8847360);            // 64 KB
    unsigned short* Wl0 = (unsigned short*)(ws + 8847360 + 65536);    // 64 KB
    unsigned short* Wh1 = (unsigned short*)(ws + 8847360 + 131072);   // 32 KB
    unsigned short* Wl1 = (unsigned short*)(ws + 8847360 + 163840);   // 32 KB
    unsigned short* Wh2 = (unsigned short*)(ws + 8847360 + 196608);   // 8 KB
    unsigned short* Wl2 = (unsigned short*)(ws + 8847360 + 204800);   // 8 KB
    _Float16* hs   = (_Float16*)(ws + 9437184);         // 25.6 MB (fp16 h*dinv)
    float* bufB    = (float*)(ws + 9437184 + 51200000); // 51.2 MB (layer outputs, fp32)
    const int* esrc = ei;
    const int* edst = ei + N_EDGES;

    const int NB = (N_NODES + 255) / 256;   // 391

    // ---- degree / dinv / CSR / W pre-split ----
    (void)hipMemsetAsync(deg, 0, N_NODES * sizeof(int), stream);
    count_deg_kernel<<<N_EDGES / 256, 256, 0, stream>>>(edst, deg);
    dinv_kernel<<<NB, 256, 0, stream>>>(deg, dinv);
    block_scan_kernel<<<NB, 256, 0, stream>>>(deg, rowptr, bsums);
    scan_bsums_kernel<<<1, 512, 0, stream>>>(bsums, NB);
    add_offsets_kernel<<<NB, 256, 0, stream>>>(rowptr, bsums, deg /*cursor*/);
    {
        const int chunks = (N_EDGES + 2047) / 2048;   // 782
        fill_slice_kernel<<<chunks * 8, 256, 0, stream>>>(esrc, edst, deg /*cursor*/, esorted);
    }
    wsplit_kernel<<<(256 * 128 + 255) / 256, 256, 0, stream>>>(W0, 256, 128, Wh0, Wl0);
    wsplit_kernel<<<(128 * 128 + 255) / 256, 256, 0, stream>>>(W1, 128, 128, Wh1, Wl1);
    wsplit_kernel<<<(128 * 32 + 255) / 256, 256, 0, stream>>>(W2, 128, 32, Wh2, Wl2);

    const int RB128 = (N_NODES + 127) / 128;   // 782

    // ---- layer 0: hs = fp16((x @ W0) * dinv) ; aggregate ----
    mfma_gemm_kernel<256, 128><<<RB128, 256, 0, stream>>>(x, Wh0, Wl0, dinv, hs);
    gather_kernel<128, 32><<<(N_NODES * 32 + 255) / 256, 256, 0, stream>>>(
        rowptr, esorted, dinv, (const f16x4*)hs, b0, bufB);

    // ---- layer 1 ----
    mfma_gemm_kernel<128, 128><<<RB128, 256, 0, stream>>>(bufB, Wh1, Wl1, dinv, hs);
    gather_kernel<128, 32><<<(N_NODES * 32 + 255) / 256, 256, 0, stream>>>(
        rowptr, esorted, dinv, (const f16x4*)hs, b1, bufB);

    // ---- layer 2: gather fused with log_softmax, writes d_out ----
    mfma_gemm_kernel<128, 32><<<RB128, 256, 0, stream>>>(bufB, Wh2, Wl2, dinv, hs);
    gather_lsm_kernel<<<(N_NODES * 8 + 255) / 256, 256, 0, stream>>>(
        rowptr, esorted, dinv, (const f16x4*)hs, b2, out);
}

// Round 9
// 411.493 us; speedup vs baseline: 15.3946x; 1.1088x over previous
//
#include <hip/hip_runtime.h>
#include <hip/hip_bf16.h>

#define N_NODES 100000
#define N_EDGES 1600000
#define SLICE_N 12500   // N_NODES / 8 dst-slices for XCD-local fill

typedef float f32x4 __attribute__((ext_vector_type(4)));
typedef _Float16 f16x8 __attribute__((ext_vector_type(8)));
typedef _Float16 f16x4 __attribute__((ext_vector_type(4)));

// ---------------- degree count (in-degree at dst) ----------------
__global__ void count_deg_kernel(const int* __restrict__ dst, int* __restrict__ deg) {
    int i = blockIdx.x * blockDim.x + threadIdx.x;
    if (i < N_EDGES) atomicAdd(&deg[dst[i]], 1);
}

__global__ void dinv_kernel(const int* __restrict__ deg, float* __restrict__ dinv) {
    int i = blockIdx.x * blockDim.x + threadIdx.x;
    if (i < N_NODES) dinv[i] = 1.0f / sqrtf((float)deg[i] + 1.0f);
}

// ---------------- CSR build: block scan -> partial scan -> add ----------------
__global__ void block_scan_kernel(const int* __restrict__ deg, int* __restrict__ rowptr,
                                  int* __restrict__ bsums) {
    __shared__ int s[256];
    int i = blockIdx.x * 256 + threadIdx.x;
    int v = (i < N_NODES) ? deg[i] : 0;
    s[threadIdx.x] = v;
    __syncthreads();
    #pragma unroll
    for (int off = 1; off < 256; off <<= 1) {
        int t = (threadIdx.x >= off) ? s[threadIdx.x - off] : 0;
        __syncthreads();
        s[threadIdx.x] += t;
        __syncthreads();
    }
    if (i < N_NODES) rowptr[i] = s[threadIdx.x] - v;   // exclusive within block
    if (threadIdx.x == 255) bsums[blockIdx.x] = s[255];
}

__global__ void scan_bsums_kernel(int* __restrict__ bsums, int nB) {
    __shared__ int s[512];
    int tid = threadIdx.x;
    int v = (tid < nB) ? bsums[tid] : 0;
    s[tid] = v;
    __syncthreads();
    #pragma unroll
    for (int off = 1; off < 512; off <<= 1) {
        int t = (tid >= off) ? s[tid - off] : 0;
        __syncthreads();
        s[tid] += t;
        __syncthreads();
    }
    if (tid < nB) bsums[tid] = s[tid] - v;             // exclusive
}

__global__ void add_offsets_kernel(int* __restrict__ rowptr, const int* __restrict__ bsums,
                                   int* __restrict__ cursor) {
    int i = blockIdx.x * 256 + threadIdx.x;
    if (i < N_NODES) {
        int r = rowptr[i] + bsums[blockIdx.x];
        rowptr[i] = r;
        cursor[i] = r;
    }
    if (i == 0) rowptr[N_NODES] = N_EDGES;
}

// dst-sliced CSR fill: block handles (slice = blk&7, chunk = blk>>3)
__global__ __launch_bounds__(256) void fill_slice_kernel(const int* __restrict__ esrc,
                                                         const int* __restrict__ edst,
                                                         int* __restrict__ cursor,
                                                         int* __restrict__ esorted) {
    const int slice = blockIdx.x & 7;
    const int chunk = blockIdx.x >> 3;
    const int base = chunk * 2048 + threadIdx.x;
    const int lo = slice * SLICE_N, hi = lo + SLICE_N;
    #pragma unroll
    for (int i = 0; i < 8; ++i) {
        int e = base + i * 256;
        if (e < N_EDGES) {
            int d = edst[e];
            if (d >= lo && d < hi) {
                int pos = atomicAdd(&cursor[d], 1);
                esorted[pos] = esrc[e];
            }
        }
    }
}

// ---------------- W[K][M] row-major -> Wt[M][K] transposed fp16 ----------------
__global__ void wconv_kernel(const float* __restrict__ W, int K, int M,
                             _Float16* __restrict__ Wt) {
    int i = blockIdx.x * 256 + threadIdx.x;
    if (i >= K * M) return;
    int k = i / M, col = i % M;
    Wt[col * K + k] = (_Float16)W[i];
}

// ---------------- LDS-free fp16 MFMA GEMM with 2-deep register pipeline ----------------
// C[r,:] = fp16( (A @ W)[r,:] * dinv[r] ); A fp32 -> fp16 in-register, W pre-converted.
// 4 waves x 32-row strips (FR=2), each wave covers all M columns (FC=M/16).
template<int K, int M>
__global__ __launch_bounds__(256) void mfma_gemm_f16(const float* __restrict__ A,
                                                     const _Float16* __restrict__ Bt,
                                                     const float* __restrict__ dinv,
                                                     _Float16* __restrict__ C) {
    constexpr int FR = 2, FC = M / 16;
    constexpr int NIT = K / 32;
    const int tid = threadIdx.x;
    const int wave = tid >> 6, lane = tid & 63;
    const int row0 = blockIdx.x * 128;
    const int r0 = wave * 32;
    const int l15 = lane & 15, kof = (lane >> 4) * 8;

    f32x4 acc[FR][FC] = {};
    int gr[FR];
    #pragma unroll
    for (int r = 0; r < FR; ++r) {
        int g = row0 + r0 + r * 16 + l15;
        gr[r] = (g < N_NODES) ? g : N_NODES - 1;
    }

    f32x4 a_cur[FR][2], a_nxt[FR][2];
    f16x8 b_cur[FC], b_nxt[FC];
    #pragma unroll
    for (int r = 0; r < FR; ++r) {
        const float* ap = A + (size_t)gr[r] * K + kof;
        a_cur[r][0] = *(const f32x4*)ap;
        a_cur[r][1] = *(const f32x4*)(ap + 4);
    }
    #pragma unroll
    for (int c = 0; c < FC; ++c)
        b_cur[c] = *(const f16x8*)(Bt + (size_t)(c * 16 + l15) * K + kof);

    #pragma unroll
    for (int it = 0; it < NIT; ++it) {
        const int k1 = (it + 1) * 32;
        if (it + 1 < NIT) {
            // issue next iteration's loads before current MFMAs
            #pragma unroll
            for (int r = 0; r < FR; ++r) {
                const float* ap = A + (size_t)gr[r] * K + k1 + kof;
                a_nxt[r][0] = *(const f32x4*)ap;
                a_nxt[r][1] = *(const f32x4*)(ap + 4);
            }
            #pragma unroll
            for (int c = 0; c < FC; ++c)
                b_nxt[c] = *(const f16x8*)(Bt + (size_t)(c * 16 + l15) * K + k1 + kof);
        }
        // convert current A to fp16
        f16x8 af[FR];
        #pragma unroll
        for (int r = 0; r < FR; ++r) {
            #pragma unroll
            for (int j = 0; j < 4; ++j) {
                af[r][j] = (_Float16)a_cur[r][0][j];
                af[r][4 + j] = (_Float16)a_cur[r][1][j];
            }
        }
        #pragma unroll
        for (int r = 0; r < FR; ++r)
            #pragma unroll
            for (int c = 0; c < FC; ++c)
                acc[r][c] = __builtin_amdgcn_mfma_f32_16x16x32_f16(af[r], b_cur[c], acc[r][c], 0, 0, 0);
        if (it + 1 < NIT) {
            #pragma unroll
            for (int r = 0; r < FR; ++r) {
                a_cur[r][0] = a_nxt[r][0];
                a_cur[r][1] = a_nxt[r][1];
            }
            #pragma unroll
            for (int c = 0; c < FC; ++c) b_cur[c] = b_nxt[c];
        }
    }

    // ---- epilogue: C/D frag layout col=lane&15, row=(lane>>4)*4+reg; fp16 store ----
    #pragma unroll
    for (int r = 0; r < FR; ++r) {
        #pragma unroll
        for (int j = 0; j < 4; ++j) {
            int g = row0 + r0 + r * 16 + (lane >> 4) * 4 + j;
            if (g >= N_NODES) continue;
            float s = dinv[g];
            #pragma unroll
            for (int c = 0; c < FC; ++c)
                C[(size_t)g * M + c * 16 + l15] = (_Float16)(acc[r][c][j] * s);
        }
    }
}

// ---------------- CSR gather: out[n] = dinv[n]*(sum hs16[src] + hs16[n]) + b ----------------
template<int M, int G>
__global__ __launch_bounds__(256) void gather_kernel(const int* __restrict__ rowptr,
                                                     const int* __restrict__ esorted,
                                                     const float* __restrict__ dinv,
                                                     const f16x4* __restrict__ hs,
                                                     const float* __restrict__ bias,
                                                     float* __restrict__ out) {
    static_assert(M == 4 * G, "layout");
    constexpr int R = M / 4;   // f16x4 chunks per row
    int gid = blockIdx.x * blockDim.x + threadIdx.x;
    int node = gid / G;
    int lane = gid % G;
    if (node >= N_NODES) return;
    int beg = rowptr[node], end = rowptr[node + 1];
    float dn = dinv[node];
    f16x4 hv = hs[(size_t)node * R + lane];   // self term
    float4 acc = make_float4((float)hv[0], (float)hv[1], (float)hv[2], (float)hv[3]);
    int j = beg;
    for (; j + 4 <= end; j += 4) {
        int s0 = esorted[j + 0];
        int s1 = esorted[j + 1];
        int s2 = esorted[j + 2];
        int s3 = esorted[j + 3];
        f16x4 v0 = hs[(size_t)s0 * R + lane];
        f16x4 v1 = hs[(size_t)s1 * R + lane];
        f16x4 v2 = hs[(size_t)s2 * R + lane];
        f16x4 v3 = hs[(size_t)s3 * R + lane];
        acc.x += ((float)v0[0] + (float)v1[0]) + ((float)v2[0] + (float)v3[0]);
        acc.y += ((float)v0[1] + (float)v1[1]) + ((float)v2[1] + (float)v3[1]);
        acc.z += ((float)v0[2] + (float)v1[2]) + ((float)v2[2] + (float)v3[2]);
        acc.w += ((float)v0[3] + (float)v1[3]) + ((float)v2[3] + (float)v3[3]);
    }
    for (; j < end; ++j) {
        int s = esorted[j];
        f16x4 v = hs[(size_t)s * R + lane];
        acc.x += (float)v[0];
        acc.y += (float)v[1];
        acc.z += (float)v[2];
        acc.w += (float)v[3];
    }
    float4 b = ((const float4*)bias)[lane];
    float4 o;
    o.x = acc.x * dn + b.x;
    o.y = acc.y * dn + b.y;
    o.z = acc.z * dn + b.z;
    o.w = acc.w * dn + b.w;
    ((float4*)out)[(size_t)node * R + lane] = o;
}

// ---------------- layer-2 gather fused with log_softmax (M=32, G=8) ----------------
__global__ __launch_bounds__(256) void gather_lsm_kernel(const int* __restrict__ rowptr,
                                                         const int* __restrict__ esorted,
                                                         const float* __restrict__ dinv,
                                                         const f16x4* __restrict__ hs,
                                                         const float* __restrict__ bias,
                                                         float* __restrict__ out) {
    constexpr int R = 8;   // f16x4 chunks per 32-wide row
    int gid = blockIdx.x * blockDim.x + threadIdx.x;
    int node = gid / 8;
    int lane = gid % 8;
    if (node >= N_NODES) return;
    int beg = rowptr[node], end = rowptr[node + 1];
    float dn = dinv[node];
    f16x4 hv = hs[(size_t)node * R + lane];
    float4 acc = make_float4((float)hv[0], (float)hv[1], (float)hv[2], (float)hv[3]);
    int j = beg;
    for (; j + 4 <= end; j += 4) {
        int s0 = esorted[j + 0];
        int s1 = esorted[j + 1];
        int s2 = esorted[j + 2];
        int s3 = esorted[j + 3];
        f16x4 v0 = hs[(size_t)s0 * R + lane];
        f16x4 v1 = hs[(size_t)s1 * R + lane];
        f16x4 v2 = hs[(size_t)s2 * R + lane];
        f16x4 v3 = hs[(size_t)s3 * R + lane];
        acc.x += ((float)v0[0] + (float)v1[0]) + ((float)v2[0] + (float)v3[0]);
        acc.y += ((float)v0[1] + (float)v1[1]) + ((float)v2[1] + (float)v3[1]);
        acc.z += ((float)v0[2] + (float)v1[2]) + ((float)v2[2] + (float)v3[2]);
        acc.w += ((float)v0[3] + (float)v1[3]) + ((float)v2[3] + (float)v3[3]);
    }
    for (; j < end; ++j) {
        int s = esorted[j];
        f16x4 v = hs[(size_t)s * R + lane];
        acc.x += (float)v[0];
        acc.y += (float)v[1];
        acc.z += (float)v[2];
        acc.w += (float)v[3];
    }
    float4 b = ((const float4*)bias)[lane];
    float4 o;
    o.x = acc.x * dn + b.x;
    o.y = acc.y * dn + b.y;
    o.z = acc.z * dn + b.z;
    o.w = acc.w * dn + b.w;
    // log_softmax over the 32-class row (8 lanes x 4)
    float m = fmaxf(fmaxf(o.x, o.y), fmaxf(o.z, o.w));
    m = fmaxf(m, __shfl_xor(m, 1, 8));
    m = fmaxf(m, __shfl_xor(m, 2, 8));
    m = fmaxf(m, __shfl_xor(m, 4, 8));
    float s = expf(o.x - m) + expf(o.y - m) + expf(o.z - m) + expf(o.w - m);
    s += __shfl_xor(s, 1, 8);
    s += __shfl_xor(s, 2, 8);
    s += __shfl_xor(s, 4, 8);
    float ls = m + logf(s);
    float4 r;
    r.x = o.x - ls; r.y = o.y - ls; r.z = o.z - ls; r.w = o.w - ls;
    ((float4*)out)[(size_t)node * R + lane] = r;
}

extern "C" void kernel_launch(void* const* d_in, const int* in_sizes, int n_in,
                              void* d_out, int out_size, void* d_ws, size_t ws_size,
                              hipStream_t stream) {
    const float* x  = (const float*)d_in[0];
    const int*   ei = (const int*)d_in[1];     // [2, E] int32
    const float* W0 = (const float*)d_in[2];
    const float* b0 = (const float*)d_in[3];
    const float* W1 = (const float*)d_in[4];
    const float* b1 = (const float*)d_in[5];
    const float* W2 = (const float*)d_in[6];
    const float* b2 = (const float*)d_in[7];
    float* out = (float*)d_out;

    char* ws = (char*)d_ws;
    float* dinv    = (float*)(ws + 0);                  // 400 KB
    int*   deg     = (int*)  (ws + (512 << 10));        // 400 KB (reused as cursor)
    int*   rowptr  = (int*)  (ws + (1 << 20));          // 400 KB + 4
    int*   bsums   = (int*)  (ws + (1536 << 10));       // ~1.6 KB
    int*   esorted = (int*)  (ws + (2 << 20));          // 6.4 MB
    _Float16* Wt0  = (_Float16*)(ws + 8847360);             // 64 KB
    _Float16* Wt1  = (_Float16*)(ws + 8847360 + 65536);     // 32 KB
    _Float16* Wt2  = (_Float16*)(ws + 8847360 + 98304);     // 8 KB
    _Float16* hs   = (_Float16*)(ws + 9437184);         // 25.6 MB (fp16 h*dinv)
    float* bufB    = (float*)(ws + 9437184 + 51200000); // 51.2 MB (layer outputs, fp32)
    const int* esrc = ei;
    const int* edst = ei + N_EDGES;

    const int NB = (N_NODES + 255) / 256;   // 391

    // ---- degree / dinv / CSR / W pre-convert ----
    (void)hipMemsetAsync(deg, 0, N_NODES * sizeof(int), stream);
    count_deg_kernel<<<N_EDGES / 256, 256, 0, stream>>>(edst, deg);
    dinv_kernel<<<NB, 256, 0, stream>>>(deg, dinv);
    block_scan_kernel<<<NB, 256, 0, stream>>>(deg, rowptr, bsums);
    scan_bsums_kernel<<<1, 512, 0, stream>>>(bsums, NB);
    add_offsets_kernel<<<NB, 256, 0, stream>>>(rowptr, bsums, deg /*cursor*/);
    {
        const int chunks = (N_EDGES + 2047) / 2048;   // 782
        fill_slice_kernel<<<chunks * 8, 256, 0, stream>>>(esrc, edst, deg /*cursor*/, esorted);
    }
    wconv_kernel<<<(256 * 128 + 255) / 256, 256, 0, stream>>>(W0, 256, 128, Wt0);
    wconv_kernel<<<(128 * 128 + 255) / 256, 256, 0, stream>>>(W1, 128, 128, Wt1);
    wconv_kernel<<<(128 * 32 + 255) / 256, 256, 0, stream>>>(W2, 128, 32, Wt2);

    const int RB128 = (N_NODES + 127) / 128;   // 782

    // ---- layer 0: hs = fp16((x @ W0) * dinv) ; aggregate ----
    mfma_gemm_f16<256, 128><<<RB128, 256, 0, stream>>>(x, Wt0, dinv, hs);
    gather_kernel<128, 32><<<(N_NODES * 32 + 255) / 256, 256, 0, stream>>>(
        rowptr, esorted, dinv, (const f16x4*)hs, b0, bufB);

    // ---- layer 1 ----
    mfma_gemm_f16<128, 128><<<RB128, 256, 0, stream>>>(bufB, Wt1, dinv, hs);
    gather_kernel<128, 32><<<(N_NODES * 32 + 255) / 256, 256, 0, stream>>>(
        rowptr, esorted, dinv, (const f16x4*)hs, b1, bufB);

    // ---- layer 2: gather fused with log_softmax, writes d_out ----
    mfma_gemm_f16<128, 32><<<RB128, 256, 0, stream>>>(bufB, Wt2, dinv, hs);
    gather_lsm_kernel<<<(N_NODES * 8 + 255) / 256, 256, 0, stream>>>(
        rowptr, esorted, dinv, (const f16x4*)hs, b2, out);
}